// Round 8
// baseline (15633.792 us; speedup 1.0000x reference)
//
#include <hip/hip_runtime.h>
#include <cstdint>
#include <cstddef>

// Problem constants
#define BB    64
#define TT    400
#define NN    1024
#define NIN   128
#define NOUT  32
#define DD    3
#define LL6   6        // ring length (delays 1,2,4; skew-1: writes t,t+1 vs reads t-1,t-2,t-4 -> diffs {1,2,3,5} mod 6)
#define GG    16       // batch groups
#define BPG   4        // batches per group
#define NT    32       // column tiles
#define KK    3072     // D*N

#define ALPHA_MEM     0.95f
#define ALPHA_MEM_OUT 0.95f
#define ALPHA_P       0.99f

// ---------------------------------------------------------------------------
__global__ void build_W(const float* __restrict__ w,
                        const float* __restrict__ w_signs,
                        const float* __restrict__ dmap,
                        float* __restrict__ W) {
    int idx = blockIdx.x * blockDim.x + threadIdx.x;
    if (idx >= DD * NN * NN) return;
    int en = idx % (NN * NN);
    int e  = en / NN;
    W[idx] = dmap[idx] * (w_signs[e] * fabsf(w[en]));
}

// inp_pre laid out [t][b][n]
__global__ void gemm_in(const float* __restrict__ inputs,
                        const float* __restrict__ w_in,
                        float* __restrict__ inp) {
    int idx = blockIdx.x * blockDim.x + threadIdx.x;
    if (idx >= TT * BB * NN) return;
    int n  = idx & (NN - 1);
    int tb = idx >> 10;
    int b  = tb & 63;
    int t  = tb >> 6;
    const float* row = inputs + ((size_t)b * TT + t) * NIN;
    float acc = 0.0f;
    #pragma unroll 8
    for (int c = 0; c < NIN; ++c)
        acc = fmaf(row[c], w_in[c * NN + n], acc);
    inp[idx] = acc;
}

// zero through the coherent point so agent-scope readers see it
__global__ void zero_sc1(float* __restrict__ p, int n) {
    int i = blockIdx.x * blockDim.x + threadIdx.x;
    if (i < n)
        __hip_atomic_store(p + i, 0.0f, __ATOMIC_RELAXED, __HIP_MEMORY_SCOPE_AGENT);
}

#define FMA16(av, wv4) do { \
    acc0.x = fmaf(av.x, wv4.x, acc0.x); acc0.y = fmaf(av.x, wv4.y, acc0.y); \
    acc0.z = fmaf(av.x, wv4.z, acc0.z); acc0.w = fmaf(av.x, wv4.w, acc0.w); \
    acc1.x = fmaf(av.y, wv4.x, acc1.x); acc1.y = fmaf(av.y, wv4.y, acc1.y); \
    acc1.z = fmaf(av.y, wv4.z, acc1.z); acc1.w = fmaf(av.y, wv4.w, acc1.w); \
    acc2.x = fmaf(av.z, wv4.x, acc2.x); acc2.y = fmaf(av.z, wv4.y, acc2.y); \
    acc2.z = fmaf(av.z, wv4.z, acc2.z); acc2.w = fmaf(av.z, wv4.w, acc2.w); \
    acc3.x = fmaf(av.w, wv4.x, acc3.x); acc3.y = fmaf(av.w, wv4.y, acc3.y); \
    acc3.z = fmaf(av.w, wv4.z, acc3.z); acc3.w = fmaf(av.w, wv4.w, acc3.w); \
} while (0)

// ---------------------------------------------------------------------------
// 512 blocks x 256 threads, 2 blocks/CU. Block (g=bid>>5, tile=bid&31) owns
// states (4 batches x 32 cols) and computes their full-k GEMM.
//
// Barrier is SPLIT into arrive (right after publish(t)+hpart(t) drained) and
// wait (after mem update): stage-A, GEMM and reduce run in the shadow of the
// other blocks' arrivals. Safety: ring is skew-1 safe (L=6, diffs {1,2,3,5});
// hpart is triple-buffered (t%3) with readout lagged one step — reader of
// slot (t-1) finishes before its own arrive(t+1), which gates writers into
// slot (t+2), so concurrent slots are always distinct mod 3.
// ---------------------------------------------------------------------------
__global__ __launch_bounds__(256, 2) void snn_scan(
    const float* __restrict__ inputs,
    const float* __restrict__ w_in,
    const float* __restrict__ w_out,
    const float* __restrict__ p,
    const int*   __restrict__ delays,
    const float* __restrict__ W,        // (KK,NN) materialized (use_W)
    const float* __restrict__ w_raw,
    const float* __restrict__ w_signs,
    const float* __restrict__ dmap,
    float*       __restrict__ ring,     // (LL6,BB,NN)
    int*         __restrict__ cnt,      // (GG*32) padded barrier counters
    float*       __restrict__ hpart,    // (3,NT,BB,NOUT)
    const float* __restrict__ inp_pre,  // (T,B,N) or null
    float*       __restrict__ out,      // (B,T,NOUT)
    int use_pre, int use_W)
{
    __shared__ __align__(16) float sa[KK * BPG];   // 48 KB; aliased as red[] post-GEMM
    __shared__ float w_out_s[32 * NOUT];           // 4 KB
    __shared__ float spk_s[BPG * 32];              // 512 B
    __shared__ float s_sign[NN];                   // 4 KB (fallback)
    __shared__ float s_in[BPG * NIN];              // 2 KB (fallback)

    const int bid  = blockIdx.x;
    const int g    = bid >> 5;          // 0..15
    const int tile = bid & 31;          // 0..31 (bid%8 = tile%8 -> XCD locality)
    const int tid  = threadIdx.x;
    const int lane = tid & 63;
    const int wv   = tid >> 6;

    const bool st = (tid < BPG * 32);   // 128 state threads
    const int  sb = tid >> 5;           // batch in group (state role)
    const int  nl = tid & 31;           // col in tile   (state role)

    const int gks = tid >> 3;           // k-split 0..31 (GEMM role)
    const int gcg = tid & 7;            // col group 0..7 (4 cols)

    float mem = 0.0f, wp = 0.0f, r = 0.0f;
    float pn = 0.0f, depr = 0.0f;
    if (st) { pn = p[tile * 32 + nl]; depr = (pn < 0.0f) ? 1.0f : 0.0f; }

    const int d0 = delays[0], d1 = delays[1], d2 = delays[2];

    for (int k = tid; k < 32 * NOUT; k += 256)
        w_out_s[k] = w_out[(tile * 32 + (k >> 5)) * NOUT + (k & 31)];
    if (!use_W)
        for (int k = tid; k < NN; k += 256) s_sign[k] = w_signs[k];
    __syncthreads();

    const float* Wt = W     + tile * 32 + gcg * 4;
    const float* Dt = dmap  + tile * 32 + gcg * 4;
    const float* Rt = w_raw + tile * 32 + gcg * 4;

    for (int t = 0; t < TT; ++t) {
        const int slot_w = t % LL6;
        const int s0 = (t - d0 + 2 * LL6) % LL6;
        const int s1 = (t - d1 + 2 * LL6) % LL6;
        const int s2 = (t - d2 + 2 * LL6) % LL6;

        // ---- phase 1: spike, publish ring (IF), wp update, ia prefetch
        bool  spk = false;
        float ia  = 0.0f;
        if (st) {
            spk = (mem - 1.0f) > 0.0f;
            const float a = spk ? (1.0f + wp) : 0.0f;
            __hip_atomic_store(ring + (((size_t)slot_w * BB + g * BPG + sb) << 10)
                                    + tile * 32 + nl,
                               a, __ATOMIC_RELAXED, __HIP_MEMORY_SCOPE_AGENT);
            wp = ALPHA_P * wp + (spk ? pn * (1.0f + depr * wp) : 0.0f);
            spk_s[tid] = spk ? 1.0f : 0.0f;
            if (use_pre)
                ia = inp_pre[((size_t)t * BB + g * BPG + sb) * NN + tile * 32 + nl];
        }
        if (!use_pre) {
            for (int k = tid; k < BPG * NIN; k += 256) {
                int b2 = k >> 7, c = k & 127;
                s_in[k] = inputs[((size_t)(g * BPG + b2) * TT + t) * NIN + c];
            }
        }
        __syncthreads();

        // ---- phase 2: readout partial for this tile (hpart slot t%3)
        if (st) {
            float h = 0.0f;
            #pragma unroll
            for (int n2 = 0; n2 < 32; ++n2)
                h = fmaf(spk_s[sb * 32 + n2], w_out_s[n2 * 32 + nl], h);
            __hip_atomic_store(hpart + ((((size_t)(t % 3) * NT + tile) * BB)
                                        + g * BPG + sb) * NOUT + nl,
                               h, __ATOMIC_RELAXED, __HIP_MEMORY_SCOPE_AGENT);
            if (!use_pre) {
                #pragma unroll 8
                for (int c = 0; c < NIN; ++c)
                    ia = fmaf(s_in[sb * NIN + c], w_in[c * NN + tile * 32 + nl], ia);
            }
        }
        __syncthreads();   // all waves' IF stores drained (vmcnt 0)

        // ---- ARRIVE (release). Wait is deferred past stage/GEMM/reduce.
        if (tid == 0)
            __hip_atomic_fetch_add(&cnt[g * 32], 1, __ATOMIC_RELEASE,
                                   __HIP_MEMORY_SCOPE_AGENT);

        // ---- readout integrate for step t-1 (overlaps the stage loads)
        if (tile == 0 && st && t > 0) {
            const int tp = (t - 1) % 3;
            float h = 0.0f;
            #pragma unroll
            for (int k3 = 0; k3 < NT; ++k3)
                h += __hip_atomic_load(hpart + ((((size_t)tp * NT + k3) * BB)
                                                + g * BPG + sb) * NOUT + nl,
                                       __ATOMIC_RELAXED, __HIP_MEMORY_SCOPE_AGENT);
            r = ALPHA_MEM_OUT * r + h;
            out[((size_t)(g * BPG + sb) * TT + (t - 1)) * NOUT + nl] = r;
        }

        // ---- stage A: 48 batched agent loads -> regs, then LDS sa[k*4+b]
        {
            const int b2 = lane >> 4;       // batch 0..3
            const int eo = lane & 15;       // e offset within 16-chunk
            float va[48];
            #pragma unroll
            for (int i = 0; i < 48; ++i) {
                const int c  = i * 4 + wv;          // 16-wide k-chunk 0..191
                const int kl = c * 16 + eo;         // k index 0..3071
                const int d  = kl >> 10;
                const int e  = kl & 1023;
                const int sl = (d == 0) ? s0 : ((d == 1) ? s1 : s2);
                va[i] = __hip_atomic_load(
                    ring + (((size_t)sl * BB + g * BPG + b2) << 10) + e,
                    __ATOMIC_RELAXED, __HIP_MEMORY_SCOPE_AGENT);
            }
            #pragma unroll
            for (int i = 0; i < 48; ++i) {
                const int kl = (i * 4 + wv) * 16 + eo;
                sa[kl * 4 + b2] = va[i];
            }
        }
        __syncthreads();

        // ---- GEMM: per thread 4 batches x 4 cols; explicit 8-deep W prefetch
        float4 acc0 = {0,0,0,0}, acc1 = {0,0,0,0}, acc2 = {0,0,0,0}, acc3 = {0,0,0,0};
        if (use_W) {
            float4 wbuf[8];
            #pragma unroll
            for (int j = 0; j < 8; ++j)
                wbuf[j] = *(const float4*)(Wt + ((size_t)(gks + (j << 5)) << 10));
            #pragma unroll 1
            for (int i8 = 0; i8 < 12; ++i8) {
                float4 wnext[8];
                if (i8 < 11) {
                    #pragma unroll
                    for (int j = 0; j < 8; ++j)
                        wnext[j] = *(const float4*)(Wt +
                            ((size_t)(gks + (((i8 + 1) * 8 + j) << 5)) << 10));
                }
                #pragma unroll
                for (int j = 0; j < 8; ++j) {
                    const int kk = gks + ((i8 * 8 + j) << 5);
                    const float4 av  = *(const float4*)&sa[kk << 2];  // 4 batches (broadcast)
                    const float4 wv4 = wbuf[j];
                    FMA16(av, wv4);
                }
                if (i8 < 11) {
                    #pragma unroll
                    for (int j = 0; j < 8; ++j) wbuf[j] = wnext[j];
                }
            }
        } else {
            #pragma unroll 2
            for (int i = 0; i < 96; ++i) {
                const int kk = gks + (i << 5);
                const int e  = kk & 1023;
                const float sg = s_sign[e];
                const float4 dm = *(const float4*)(Dt + ((size_t)kk << 10));
                const float4 wr = *(const float4*)(Rt + ((size_t)e << 10));
                float4 wv4;
                wv4.x = dm.x * (sg * fabsf(wr.x));
                wv4.y = dm.y * (sg * fabsf(wr.y));
                wv4.z = dm.z * (sg * fabsf(wr.z));
                wv4.w = dm.w * (sg * fabsf(wr.w));
                const float4 av = *(const float4*)&sa[kk << 2];
                FMA16(av, wv4);
            }
        }
        __syncthreads();             // sa reads done; alias as red

        float* red = sa;             // red[o][33], o = b2*32 + gcg*4 + j  (o<128)
        {
            const int o0 = gcg * 4;
            red[(0 * 32 + o0 + 0) * 33 + gks] = acc0.x;
            red[(0 * 32 + o0 + 1) * 33 + gks] = acc0.y;
            red[(0 * 32 + o0 + 2) * 33 + gks] = acc0.z;
            red[(0 * 32 + o0 + 3) * 33 + gks] = acc0.w;
            red[(1 * 32 + o0 + 0) * 33 + gks] = acc1.x;
            red[(1 * 32 + o0 + 1) * 33 + gks] = acc1.y;
            red[(1 * 32 + o0 + 2) * 33 + gks] = acc1.z;
            red[(1 * 32 + o0 + 3) * 33 + gks] = acc1.w;
            red[(2 * 32 + o0 + 0) * 33 + gks] = acc2.x;
            red[(2 * 32 + o0 + 1) * 33 + gks] = acc2.y;
            red[(2 * 32 + o0 + 2) * 33 + gks] = acc2.z;
            red[(2 * 32 + o0 + 3) * 33 + gks] = acc2.w;
            red[(3 * 32 + o0 + 0) * 33 + gks] = acc3.x;
            red[(3 * 32 + o0 + 1) * 33 + gks] = acc3.y;
            red[(3 * 32 + o0 + 2) * 33 + gks] = acc3.z;
            red[(3 * 32 + o0 + 3) * 33 + gks] = acc3.w;
        }
        __syncthreads();

        if (st) {
            float syn = 0.0f;
            #pragma unroll
            for (int k2 = 0; k2 < 32; ++k2)
                syn += red[tid * 33 + k2];
            mem = ALPHA_MEM * mem + ia + syn - (spk ? 1.0f : 0.0f);
        }
        __syncthreads();             // red reads done before next staging

        // ---- WAIT: straggler time was overlapped with stage/GEMM/reduce
        if (tid == 0) {
            const int target = 32 * (t + 1);
            while (__hip_atomic_load(&cnt[g * 32], __ATOMIC_ACQUIRE,
                                     __HIP_MEMORY_SCOPE_AGENT) < target)
                __builtin_amdgcn_s_sleep(2);
        }
        __syncthreads();
    }

    // ---- tail readout for t = TT-1 (final wait already passed)
    if (tile == 0 && st) {
        const int tp = (TT - 1) % 3;
        float h = 0.0f;
        #pragma unroll
        for (int k3 = 0; k3 < NT; ++k3)
            h += __hip_atomic_load(hpart + ((((size_t)tp * NT + k3) * BB)
                                            + g * BPG + sb) * NOUT + nl,
                                   __ATOMIC_RELAXED, __HIP_MEMORY_SCOPE_AGENT);
        r = ALPHA_MEM_OUT * r + h;
        out[((size_t)(g * BPG + sb) * TT + (TT - 1)) * NOUT + nl] = r;
    }
}

// ---------------------------------------------------------------------------
extern "C" void kernel_launch(void* const* d_in, const int* in_sizes, int n_in,
                              void* d_out, int out_size, void* d_ws, size_t ws_size,
                              hipStream_t stream) {
    const float* inputs  = (const float*)d_in[0];
    const float* w       = (const float*)d_in[1];
    const float* w_in    = (const float*)d_in[2];
    const float* w_out   = (const float*)d_in[3];
    const float* w_signs = (const float*)d_in[4];
    const float* dmap    = (const float*)d_in[5];
    const float* p       = (const float*)d_in[6];
    const int*   delays  = (const int*)d_in[7];
    float*       outp    = (float*)d_out;

    // ws layout (floats): ring | cnt(padded) | hpart(x3) | W | inp_pre
    const size_t ring_f = (size_t)LL6 * BB * NN;          // 393216
    const size_t cnt_f  = GG * 32;                        // 512
    const size_t hp_f   = (size_t)3 * NT * BB * NOUT;     // 196608
    const size_t W_f    = (size_t)DD * NN * NN;           // 3145728
    const size_t pre_f  = (size_t)TT * BB * NN;           // 26214400

    float* ws = (float*)d_ws;
    float* ring  = ws;
    int*   cntp  = (int*)(ws + ring_f);
    float* hpart = ws + ring_f + cnt_f;
    size_t used  = ring_f + cnt_f + hp_f;

    int use_W = 0, use_pre = 0;
    float *W = nullptr, *inp_pre = nullptr;
    if (ws_size >= (used + W_f) * 4)   { use_W = 1;   W = ws + used;       used += W_f; }
    if (ws_size >= (used + pre_f) * 4) { use_pre = 1; inp_pre = ws + used; used += pre_f; }

    if (use_W) {
        const int total = DD * NN * NN;
        build_W<<<(total + 255) / 256, 256, 0, stream>>>(w, w_signs, dmap, W);
    }
    if (use_pre) {
        const int total = TT * BB * NN;
        gemm_in<<<(total + 255) / 256, 256, 0, stream>>>(inputs, w_in, inp_pre);
    }
    {
        const int total = (int)(ring_f + cnt_f);   // ring + counters
        zero_sc1<<<(total + 255) / 256, 256, 0, stream>>>(ring, total);
    }

    void* args[] = {
        (void*)&inputs, (void*)&w_in, (void*)&w_out, (void*)&p, (void*)&delays,
        (void*)&W, (void*)&w, (void*)&w_signs, (void*)&dmap,
        (void*)&ring, (void*)&cntp, (void*)&hpart, (void*)&inp_pre, (void*)&outp,
        (void*)&use_pre, (void*)&use_W
    };
    hipError_t cerr = hipLaunchCooperativeKernel((const void*)snn_scan,
                               dim3(GG * NT), dim3(256), args, 0, stream);
    if (cerr != hipSuccess) {
        // Cooperative launch rejected: fall back to a plain launch. 512 blocks
        // at 2 blocks/CU (LDS-limited) on 256 CUs are co-resident physically,
        // so the agent-scope spin barrier still functions.
        hipLaunchKernelGGL(snn_scan, dim3(GG * NT), dim3(256), 0, stream,
                           inputs, w_in, w_out, p, delays, W, w, w_signs, dmap,
                           ring, cntp, hpart, inp_pre, outp, use_pre, use_W);
    }
}

// Round 9
// 11378.323 us; speedup vs baseline: 1.3740x; 1.3740x over previous
//
#include <hip/hip_runtime.h>
#include <cstdint>
#include <cstddef>

// Problem constants
#define BB    64
#define TT    400
#define NN    1024
#define NIN   128
#define NOUT  32
#define DD    3
#define LL6   6        // ring length (delays 1,2,4)
#define GG    16       // batch groups
#define BPG   4        // batches per group
#define NT    32       // column tiles
#define KK    3072     // D*N

#define ALPHA_MEM     0.95f
#define ALPHA_MEM_OUT 0.95f
#define ALPHA_P       0.99f

// ---------------------------------------------------------------------------
__global__ void build_W(const float* __restrict__ w,
                        const float* __restrict__ w_signs,
                        const float* __restrict__ dmap,
                        float* __restrict__ W) {
    int idx = blockIdx.x * blockDim.x + threadIdx.x;
    if (idx >= DD * NN * NN) return;
    int en = idx % (NN * NN);
    int e  = en / NN;
    W[idx] = dmap[idx] * (w_signs[e] * fabsf(w[en]));
}

// inp_pre laid out [t][b][n]
__global__ void gemm_in(const float* __restrict__ inputs,
                        const float* __restrict__ w_in,
                        float* __restrict__ inp) {
    int idx = blockIdx.x * blockDim.x + threadIdx.x;
    if (idx >= TT * BB * NN) return;
    int n  = idx & (NN - 1);
    int tb = idx >> 10;
    int b  = tb & 63;
    int t  = tb >> 6;
    const float* row = inputs + ((size_t)b * TT + t) * NIN;
    float acc = 0.0f;
    #pragma unroll 8
    for (int c = 0; c < NIN; ++c)
        acc = fmaf(row[c], w_in[c * NN + n], acc);
    inp[idx] = acc;
}

// zero through the coherent point so agent-scope readers see it
__global__ void zero_sc1(float* __restrict__ p, int n) {
    int i = blockIdx.x * blockDim.x + threadIdx.x;
    if (i < n)
        __hip_atomic_store(p + i, 0.0f, __ATOMIC_RELAXED, __HIP_MEMORY_SCOPE_AGENT);
}

// ---------------------------------------------------------------------------
// 512 blocks x 256 threads, 2 blocks/CU. Block (g=bid>>5, tile=bid&31) owns
// states (4 batches x 32 cols) and computes their full-k GEMM.
//
// R9 = R7 with ONE structural change: the group barrier is split so stage-A
// runs between arrive and wait (straggler spread hides under stage latency).
// Protocol safety for this exact order (verified):
//   stage(t) reads slots {t-1,t-2,t-4}%6; concurrent publishers are
//   publish(t) (diffs {1,2,4}) and publish(t+1) (diffs {2,3,5}) - all != 0.
//   publish(t) overwrites slot read by stage(t-2): B.stage(t-2) <
//   B.arrive(t-1) <= A.wait(t-1) < A.publish(t).  hpart mod-2: overwriter
//   phase2(t+2) needs wait(t+1) <- A.arrive(t+1) which follows A.readout(t).
// Everything else (interleaved stage unroll 16, GEMM unroll 8, in-step
// mod-2 readout, host fallback) is byte-identical to R7.
// ---------------------------------------------------------------------------
__global__ __launch_bounds__(256, 2) void snn_scan(
    const float* __restrict__ inputs,
    const float* __restrict__ w_in,
    const float* __restrict__ w_out,
    const float* __restrict__ p,
    const int*   __restrict__ delays,
    const float* __restrict__ W,        // (KK,NN) materialized (use_W)
    const float* __restrict__ w_raw,
    const float* __restrict__ w_signs,
    const float* __restrict__ dmap,
    float*       __restrict__ ring,     // (LL6,BB,NN)
    int*         __restrict__ cnt,      // (GG*32) padded barrier counters
    float*       __restrict__ hpart,    // (2,NT,BB,NOUT)
    const float* __restrict__ inp_pre,  // (T,B,N) or null
    float*       __restrict__ out,      // (B,T,NOUT)
    int use_pre, int use_W)
{
    __shared__ __align__(16) float sa[KK * BPG];   // 48 KB; aliased as red[] post-GEMM
    __shared__ float w_out_s[32 * NOUT];           // 4 KB
    __shared__ float spk_s[BPG * 32];              // 512 B
    __shared__ float s_sign[NN];                   // 4 KB (fallback)
    __shared__ float s_in[BPG * NIN];              // 2 KB (fallback)

    const int bid  = blockIdx.x;
    const int g    = bid >> 5;          // 0..15
    const int tile = bid & 31;          // 0..31 (bid%8 = tile%8 -> XCD locality)
    const int tid  = threadIdx.x;
    const int lane = tid & 63;
    const int wv   = tid >> 6;

    const bool st = (tid < BPG * 32);   // 128 state threads
    const int  sb = tid >> 5;           // batch in group (state role)
    const int  nl = tid & 31;           // col in tile   (state role)

    const int gks = tid >> 3;           // k-split 0..31 (GEMM role)
    const int gcg = tid & 7;            // col group 0..7 (4 cols)

    float mem = 0.0f, wp = 0.0f, r = 0.0f;
    float pn = 0.0f, depr = 0.0f;
    if (st) { pn = p[tile * 32 + nl]; depr = (pn < 0.0f) ? 1.0f : 0.0f; }

    const int d0 = delays[0], d1 = delays[1], d2 = delays[2];

    for (int k = tid; k < 32 * NOUT; k += 256)
        w_out_s[k] = w_out[(tile * 32 + (k >> 5)) * NOUT + (k & 31)];
    if (!use_W)
        for (int k = tid; k < NN; k += 256) s_sign[k] = w_signs[k];
    __syncthreads();

    const float* Wt = W     + tile * 32 + gcg * 4;
    const float* Dt = dmap  + tile * 32 + gcg * 4;
    const float* Rt = w_raw + tile * 32 + gcg * 4;

    for (int t = 0; t < TT; ++t) {
        const int slot_w = t % LL6;
        const int s0 = (t - d0 + 2 * LL6) % LL6;
        const int s1 = (t - d1 + 2 * LL6) % LL6;
        const int s2 = (t - d2 + 2 * LL6) % LL6;

        // ---- phase 1: spike, publish ring (IF), wp update, ia prefetch
        bool  spk = false;
        float ia  = 0.0f;
        if (st) {
            spk = (mem - 1.0f) > 0.0f;
            const float a = spk ? (1.0f + wp) : 0.0f;
            __hip_atomic_store(ring + (((size_t)slot_w * BB + g * BPG + sb) << 10)
                                    + tile * 32 + nl,
                               a, __ATOMIC_RELAXED, __HIP_MEMORY_SCOPE_AGENT);
            wp = ALPHA_P * wp + (spk ? pn * (1.0f + depr * wp) : 0.0f);
            spk_s[tid] = spk ? 1.0f : 0.0f;
            if (use_pre)
                ia = inp_pre[((size_t)t * BB + g * BPG + sb) * NN + tile * 32 + nl];
        }
        if (!use_pre) {
            for (int k = tid; k < BPG * NIN; k += 256) {
                int b2 = k >> 7, c = k & 127;
                s_in[k] = inputs[((size_t)(g * BPG + b2) * TT + t) * NIN + c];
            }
        }
        __syncthreads();

        // ---- phase 2: readout partial for this tile
        if (st) {
            float h = 0.0f;
            #pragma unroll
            for (int n2 = 0; n2 < 32; ++n2)
                h = fmaf(spk_s[sb * 32 + n2], w_out_s[n2 * 32 + nl], h);
            __hip_atomic_store(hpart + ((((size_t)(t & 1) * NT + tile) * BB)
                                        + g * BPG + sb) * NOUT + nl,
                               h, __ATOMIC_RELAXED, __HIP_MEMORY_SCOPE_AGENT);
            if (!use_pre) {
                #pragma unroll 8
                for (int c = 0; c < NIN; ++c)
                    ia = fmaf(s_in[sb * NIN + c], w_in[c * NN + tile * 32 + nl], ia);
            }
        }
        __syncthreads();   // all waves' IF stores drained (vmcnt 0) before arrive

        // ---- ARRIVE (release); wait deferred past stage-A
        if (tid == 0)
            __hip_atomic_fetch_add(&cnt[g * 32], 1, __ATOMIC_RELEASE,
                                   __HIP_MEMORY_SCOPE_AGENT);

        // ---- stage A transposed: sa[k*4 + b] (needs only barrier(t-1))
        {
            const int b2 = lane >> 4;       // batch 0..3
            const int eo = lane & 15;       // e offset within 16-chunk
            #pragma unroll 16
            for (int i = 0; i < 48; ++i) {
                const int c  = i * 4 + wv;          // 16-wide k-chunk 0..191
                const int kl = c * 16 + eo;         // k index 0..3071
                const int d  = kl >> 10;
                const int e  = kl & 1023;
                const int sl = (d == 0) ? s0 : ((d == 1) ? s1 : s2);
                const float v = __hip_atomic_load(
                    ring + (((size_t)sl * BB + g * BPG + b2) << 10) + e,
                    __ATOMIC_RELAXED, __HIP_MEMORY_SCOPE_AGENT);
                sa[kl * 4 + b2] = v;
            }
        }
        __syncthreads();

        // ---- WAIT: straggler spread was hidden under stage-A
        if (tid == 0) {
            const int target = 32 * (t + 1);
            while (__hip_atomic_load(&cnt[g * 32], __ATOMIC_ACQUIRE,
                                     __HIP_MEMORY_SCOPE_AGENT) < target)
                __builtin_amdgcn_s_sleep(2);
        }
        __syncthreads();

        // ---- readout (tile-0 block of each group): integrate step t
        if (tile == 0 && st) {
            float h = 0.0f;
            #pragma unroll
            for (int k3 = 0; k3 < NT; ++k3)
                h += __hip_atomic_load(hpart + ((((size_t)(t & 1) * NT + k3) * BB)
                                                + g * BPG + sb) * NOUT + nl,
                                       __ATOMIC_RELAXED, __HIP_MEMORY_SCOPE_AGENT);
            r = ALPHA_MEM_OUT * r + h;
            out[((size_t)(g * BPG + sb) * TT + t) * NOUT + nl] = r;
        }

        // ---- GEMM: per thread 4 batches x 4 cols, k interleaved (gks + 32i)
        float4 acc0 = {0,0,0,0}, acc1 = {0,0,0,0}, acc2 = {0,0,0,0}, acc3 = {0,0,0,0};
        if (use_W) {
            #pragma unroll 8
            for (int i = 0; i < 96; ++i) {
                const int kk = gks + (i << 5);
                const float4 av = *(const float4*)&sa[kk << 2];          // 4 batches (broadcast)
                const float4 wv4 = *(const float4*)(Wt + ((size_t)kk << 10)); // 4 cols (L2)
                acc0.x = fmaf(av.x, wv4.x, acc0.x); acc0.y = fmaf(av.x, wv4.y, acc0.y);
                acc0.z = fmaf(av.x, wv4.z, acc0.z); acc0.w = fmaf(av.x, wv4.w, acc0.w);
                acc1.x = fmaf(av.y, wv4.x, acc1.x); acc1.y = fmaf(av.y, wv4.y, acc1.y);
                acc1.z = fmaf(av.y, wv4.z, acc1.z); acc1.w = fmaf(av.y, wv4.w, acc1.w);
                acc2.x = fmaf(av.z, wv4.x, acc2.x); acc2.y = fmaf(av.z, wv4.y, acc2.y);
                acc2.z = fmaf(av.z, wv4.z, acc2.z); acc2.w = fmaf(av.z, wv4.w, acc2.w);
                acc3.x = fmaf(av.w, wv4.x, acc3.x); acc3.y = fmaf(av.w, wv4.y, acc3.y);
                acc3.z = fmaf(av.w, wv4.z, acc3.z); acc3.w = fmaf(av.w, wv4.w, acc3.w);
            }
        } else {
            #pragma unroll 2
            for (int i = 0; i < 96; ++i) {
                const int kk = gks + (i << 5);
                const int e  = kk & 1023;
                const float sg = s_sign[e];
                const float4 dm = *(const float4*)(Dt + ((size_t)kk << 10));
                const float4 wr = *(const float4*)(Rt + ((size_t)e << 10));
                float4 wv4;
                wv4.x = dm.x * (sg * fabsf(wr.x));
                wv4.y = dm.y * (sg * fabsf(wr.y));
                wv4.z = dm.z * (sg * fabsf(wr.z));
                wv4.w = dm.w * (sg * fabsf(wr.w));
                const float4 av = *(const float4*)&sa[kk << 2];
                acc0.x = fmaf(av.x, wv4.x, acc0.x); acc0.y = fmaf(av.x, wv4.y, acc0.y);
                acc0.z = fmaf(av.x, wv4.z, acc0.z); acc0.w = fmaf(av.x, wv4.w, acc0.w);
                acc1.x = fmaf(av.y, wv4.x, acc1.x); acc1.y = fmaf(av.y, wv4.y, acc1.y);
                acc1.z = fmaf(av.y, wv4.z, acc1.z); acc1.w = fmaf(av.y, wv4.w, acc1.w);
                acc2.x = fmaf(av.z, wv4.x, acc2.x); acc2.y = fmaf(av.z, wv4.y, acc2.y);
                acc2.z = fmaf(av.z, wv4.z, acc2.z); acc2.w = fmaf(av.z, wv4.w, acc2.w);
                acc3.x = fmaf(av.w, wv4.x, acc3.x); acc3.y = fmaf(av.w, wv4.y, acc3.y);
                acc3.z = fmaf(av.w, wv4.z, acc3.z); acc3.w = fmaf(av.w, wv4.w, acc3.w);
            }
        }
        __syncthreads();             // sa reads done; alias as red

        float* red = sa;             // red[o][33], o = b2*32 + gcg*4 + j  (o<128)
        {
            const int o0 = gcg * 4;
            red[(0 * 32 + o0 + 0) * 33 + gks] = acc0.x;
            red[(0 * 32 + o0 + 1) * 33 + gks] = acc0.y;
            red[(0 * 32 + o0 + 2) * 33 + gks] = acc0.z;
            red[(0 * 32 + o0 + 3) * 33 + gks] = acc0.w;
            red[(1 * 32 + o0 + 0) * 33 + gks] = acc1.x;
            red[(1 * 32 + o0 + 1) * 33 + gks] = acc1.y;
            red[(1 * 32 + o0 + 2) * 33 + gks] = acc1.z;
            red[(1 * 32 + o0 + 3) * 33 + gks] = acc1.w;
            red[(2 * 32 + o0 + 0) * 33 + gks] = acc2.x;
            red[(2 * 32 + o0 + 1) * 33 + gks] = acc2.y;
            red[(2 * 32 + o0 + 2) * 33 + gks] = acc2.z;
            red[(2 * 32 + o0 + 3) * 33 + gks] = acc2.w;
            red[(3 * 32 + o0 + 0) * 33 + gks] = acc3.x;
            red[(3 * 32 + o0 + 1) * 33 + gks] = acc3.y;
            red[(3 * 32 + o0 + 2) * 33 + gks] = acc3.z;
            red[(3 * 32 + o0 + 3) * 33 + gks] = acc3.w;
        }
        __syncthreads();

        if (st) {
            float syn = 0.0f;
            #pragma unroll
            for (int k2 = 0; k2 < 32; ++k2)
                syn += red[tid * 33 + k2];
            mem = ALPHA_MEM * mem + ia + syn - (spk ? 1.0f : 0.0f);
        }
        __syncthreads();             // red reads done before next staging
    }
}

// ---------------------------------------------------------------------------
extern "C" void kernel_launch(void* const* d_in, const int* in_sizes, int n_in,
                              void* d_out, int out_size, void* d_ws, size_t ws_size,
                              hipStream_t stream) {
    const float* inputs  = (const float*)d_in[0];
    const float* w       = (const float*)d_in[1];
    const float* w_in    = (const float*)d_in[2];
    const float* w_out   = (const float*)d_in[3];
    const float* w_signs = (const float*)d_in[4];
    const float* dmap    = (const float*)d_in[5];
    const float* p       = (const float*)d_in[6];
    const int*   delays  = (const int*)d_in[7];
    float*       outp    = (float*)d_out;

    // ws layout (floats): ring | cnt(padded) | hpart | W | inp_pre
    const size_t ring_f = (size_t)LL6 * BB * NN;          // 393216
    const size_t cnt_f  = GG * 32;                        // 512
    const size_t hp_f   = (size_t)2 * NT * BB * NOUT;     // 131072
    const size_t W_f    = (size_t)DD * NN * NN;           // 3145728
    const size_t pre_f  = (size_t)TT * BB * NN;           // 26214400

    float* ws = (float*)d_ws;
    float* ring  = ws;
    int*   cntp  = (int*)(ws + ring_f);
    float* hpart = ws + ring_f + cnt_f;
    size_t used  = ring_f + cnt_f + hp_f;

    int use_W = 0, use_pre = 0;
    float *W = nullptr, *inp_pre = nullptr;
    if (ws_size >= (used + W_f) * 4)   { use_W = 1;   W = ws + used;       used += W_f; }
    if (ws_size >= (used + pre_f) * 4) { use_pre = 1; inp_pre = ws + used; used += pre_f; }

    if (use_W) {
        const int total = DD * NN * NN;
        build_W<<<(total + 255) / 256, 256, 0, stream>>>(w, w_signs, dmap, W);
    }
    if (use_pre) {
        const int total = TT * BB * NN;
        gemm_in<<<(total + 255) / 256, 256, 0, stream>>>(inputs, w_in, inp_pre);
    }
    {
        const int total = (int)(ring_f + cnt_f);   // ring + counters
        zero_sc1<<<(total + 255) / 256, 256, 0, stream>>>(ring, total);
    }

    void* args[] = {
        (void*)&inputs, (void*)&w_in, (void*)&w_out, (void*)&p, (void*)&delays,
        (void*)&W, (void*)&w, (void*)&w_signs, (void*)&dmap,
        (void*)&ring, (void*)&cntp, (void*)&hpart, (void*)&inp_pre, (void*)&outp,
        (void*)&use_pre, (void*)&use_W
    };
    hipError_t cerr = hipLaunchCooperativeKernel((const void*)snn_scan,
                               dim3(GG * NT), dim3(256), args, 0, stream);
    if (cerr != hipSuccess) {
        // Cooperative launch rejected: fall back to a plain launch. 512 blocks
        // at 2 blocks/CU (LDS-limited) on 256 CUs are co-resident physically,
        // so the agent-scope spin barrier still functions.
        hipLaunchKernelGGL(snn_scan, dim3(GG * NT), dim3(256), 0, stream,
                           inputs, w_in, w_out, p, delays, W, w, w_signs, dmap,
                           ring, cntp, hpart, inp_pre, outp, use_pre, use_W);
    }
}

// Round 10
// 10945.885 us; speedup vs baseline: 1.4283x; 1.0395x over previous
//
#include <hip/hip_runtime.h>
#include <cstdint>
#include <cstddef>

// Problem constants
#define BB    64
#define TT    400
#define NN    1024
#define NIN   128
#define NOUT  32
#define DD    3
#define LL6   6        // ring length (delays 1,2,4)
#define GG    16       // batch groups
#define BPG   4        // batches per group
#define NT    32       // column tiles
#define KK    3072     // D*N
#define CAP   800      // CSR capacity per column (mean 614, +8 sigma)

#define ALPHA_MEM     0.95f
#define ALPHA_MEM_OUT 0.95f
#define ALPHA_P       0.99f

// ---------------------------------------------------------------------------
__global__ void build_W(const float* __restrict__ w,
                        const float* __restrict__ w_signs,
                        const float* __restrict__ dmap,
                        float* __restrict__ W) {
    int idx = blockIdx.x * blockDim.x + threadIdx.x;
    if (idx >= DD * NN * NN) return;
    int en = idx % (NN * NN);
    int e  = en / NN;
    W[idx] = dmap[idx] * (w_signs[e] * fabsf(w[en]));
}

// Per-column CSR: pack[col][slot] = {u32 k, f32 val}, ascending k, zero-padded
// to CAP. Values bit-identical to dense W.
__global__ void build_csr(const float* __restrict__ W,
                          uint2* __restrict__ pack) {
    const int col = blockIdx.x;           // 0..1023
    const int tid = threadIdx.x;          // 256 threads, 12 ks each
    __shared__ int pref[256];
    __shared__ int total_s;

    int cnt = 0;
    #pragma unroll
    for (int i = 0; i < 12; ++i) {
        const float v = W[(size_t)(tid * 12 + i) * NN + col];
        cnt += (v != 0.0f) ? 1 : 0;
    }
    pref[tid] = cnt;
    __syncthreads();
    if (tid == 0) {
        int run = 0;
        for (int j = 0; j < 256; ++j) { int c = pref[j]; pref[j] = run; run += c; }
        total_s = run;
    }
    __syncthreads();

    int ofs = pref[tid];
    #pragma unroll
    for (int i = 0; i < 12; ++i) {
        const int k = tid * 12 + i;
        const float v = W[(size_t)k * NN + col];
        if (v != 0.0f && ofs < CAP) {
            pack[(size_t)col * CAP + ofs] = make_uint2((unsigned)k, __float_as_uint(v));
            ++ofs;
        }
    }
    for (int s = total_s + tid; s < CAP; s += 256)
        pack[(size_t)col * CAP + s] = make_uint2(0u, 0u);   // k=0, v=0.0f
}

// inp_pre laid out [t][b][n]
__global__ void gemm_in(const float* __restrict__ inputs,
                        const float* __restrict__ w_in,
                        float* __restrict__ inp) {
    int idx = blockIdx.x * blockDim.x + threadIdx.x;
    if (idx >= TT * BB * NN) return;
    int n  = idx & (NN - 1);
    int tb = idx >> 10;
    int b  = tb & 63;
    int t  = tb >> 6;
    const float* row = inputs + ((size_t)b * TT + t) * NIN;
    float acc = 0.0f;
    #pragma unroll 8
    for (int c = 0; c < NIN; ++c)
        acc = fmaf(row[c], w_in[c * NN + n], acc);
    inp[idx] = acc;
}

// zero through the coherent point so agent-scope readers see it
__global__ void zero_sc1(float* __restrict__ p, int n) {
    int i = blockIdx.x * blockDim.x + threadIdx.x;
    if (i < n)
        __hip_atomic_store(p + i, 0.0f, __ATOMIC_RELAXED, __HIP_MEMORY_SCOPE_AGENT);
}

// ---------------------------------------------------------------------------
// 512 blocks x 256 threads, 2 blocks/CU. Block (g=bid>>5, tile=bid&31) owns
// states (4 batches x 32 cols). Barrier/stage structure identical to R9
// (verified PASS). R10 delta: GEMM uses the 20%-dense CSR of W (2x less L2
// traffic, 2.7x fewer issue ops, 8-wide instead of 32-wide reduction).
// ---------------------------------------------------------------------------
__global__ __launch_bounds__(256, 2) void snn_scan(
    const float* __restrict__ inputs,
    const float* __restrict__ w_in,
    const float* __restrict__ w_out,
    const float* __restrict__ p,
    const int*   __restrict__ delays,
    const float* __restrict__ W,        // (KK,NN) materialized (use_W)
    const float* __restrict__ w_raw,
    const float* __restrict__ w_signs,
    const float* __restrict__ dmap,
    float*       __restrict__ ring,     // (LL6,BB,NN)
    int*         __restrict__ cnt,      // (GG*32) padded barrier counters
    float*       __restrict__ hpart,    // (2,NT,BB,NOUT)
    const float* __restrict__ inp_pre,  // (T,B,N) or null
    const uint2* __restrict__ pack,     // (NN,CAP) CSR or null
    float*       __restrict__ out,      // (B,T,NOUT)
    int use_pre, int use_W, int use_csr)
{
    __shared__ __align__(16) float sa[KK * BPG];   // 48 KB; aliased as red[] post-GEMM
    __shared__ float w_out_s[32 * NOUT];           // 4 KB
    __shared__ float spk_s[BPG * 32];              // 512 B
    __shared__ float s_sign[NN];                   // 4 KB (fallback)
    __shared__ float s_in[BPG * NIN];              // 2 KB (fallback)

    const int bid  = blockIdx.x;
    const int g    = bid >> 5;          // 0..15
    const int tile = bid & 31;          // 0..31 (bid%8 = tile%8 -> XCD locality)
    const int tid  = threadIdx.x;
    const int lane = tid & 63;
    const int wv   = tid >> 6;

    const bool st = (tid < BPG * 32);   // 128 state threads
    const int  sb = tid >> 5;           // batch in group (state role)
    const int  nl = tid & 31;           // col in tile   (state role)

    const int gks = tid >> 3;           // k-split 0..31 (dense GEMM role)
    const int gcg = tid & 7;            // col group 0..7 (dense GEMM role)

    const int colg = tid >> 3;          // 0..31: column owned (sparse role)
    const int sub  = tid & 7;           // 0..7 : nz-split  (sparse role)

    float mem = 0.0f, wp = 0.0f, r = 0.0f;
    float pn = 0.0f, depr = 0.0f;
    if (st) { pn = p[tile * 32 + nl]; depr = (pn < 0.0f) ? 1.0f : 0.0f; }

    const int d0 = delays[0], d1 = delays[1], d2 = delays[2];

    for (int k = tid; k < 32 * NOUT; k += 256)
        w_out_s[k] = w_out[(tile * 32 + (k >> 5)) * NOUT + (k & 31)];
    if (!use_W)
        for (int k = tid; k < NN; k += 256) s_sign[k] = w_signs[k];
    __syncthreads();

    const float* Wt = W     + tile * 32 + gcg * 4;
    const float* Dt = dmap  + tile * 32 + gcg * 4;
    const float* Rt = w_raw + tile * 32 + gcg * 4;
    const uint2* Pk = pack  + (size_t)(tile * 32 + colg) * CAP;

    for (int t = 0; t < TT; ++t) {
        const int slot_w = t % LL6;
        const int s0 = (t - d0 + 2 * LL6) % LL6;
        const int s1 = (t - d1 + 2 * LL6) % LL6;
        const int s2 = (t - d2 + 2 * LL6) % LL6;

        // ---- phase 1: spike, publish ring (IF), wp update, ia prefetch
        bool  spk = false;
        float ia  = 0.0f;
        if (st) {
            spk = (mem - 1.0f) > 0.0f;
            const float a = spk ? (1.0f + wp) : 0.0f;
            __hip_atomic_store(ring + (((size_t)slot_w * BB + g * BPG + sb) << 10)
                                    + tile * 32 + nl,
                               a, __ATOMIC_RELAXED, __HIP_MEMORY_SCOPE_AGENT);
            wp = ALPHA_P * wp + (spk ? pn * (1.0f + depr * wp) : 0.0f);
            spk_s[tid] = spk ? 1.0f : 0.0f;
            if (use_pre)
                ia = inp_pre[((size_t)t * BB + g * BPG + sb) * NN + tile * 32 + nl];
        }
        if (!use_pre) {
            for (int k = tid; k < BPG * NIN; k += 256) {
                int b2 = k >> 7, c = k & 127;
                s_in[k] = inputs[((size_t)(g * BPG + b2) * TT + t) * NIN + c];
            }
        }
        __syncthreads();

        // ---- phase 2: readout partial for this tile
        if (st) {
            float h = 0.0f;
            #pragma unroll
            for (int n2 = 0; n2 < 32; ++n2)
                h = fmaf(spk_s[sb * 32 + n2], w_out_s[n2 * 32 + nl], h);
            __hip_atomic_store(hpart + ((((size_t)(t & 1) * NT + tile) * BB)
                                        + g * BPG + sb) * NOUT + nl,
                               h, __ATOMIC_RELAXED, __HIP_MEMORY_SCOPE_AGENT);
            if (!use_pre) {
                #pragma unroll 8
                for (int c = 0; c < NIN; ++c)
                    ia = fmaf(s_in[sb * NIN + c], w_in[c * NN + tile * 32 + nl], ia);
            }
        }
        __syncthreads();   // all waves' IF stores drained (vmcnt 0) before arrive

        // ---- ARRIVE (release); wait deferred past stage-A
        if (tid == 0)
            __hip_atomic_fetch_add(&cnt[g * 32], 1, __ATOMIC_RELEASE,
                                   __HIP_MEMORY_SCOPE_AGENT);

        // ---- stage A transposed: sa[k*4 + b] (needs only barrier(t-1))
        {
            const int b2 = lane >> 4;       // batch 0..3
            const int eo = lane & 15;       // e offset within 16-chunk
            #pragma unroll 16
            for (int i = 0; i < 48; ++i) {
                const int c  = i * 4 + wv;          // 16-wide k-chunk 0..191
                const int kl = c * 16 + eo;         // k index 0..3071
                const int d  = kl >> 10;
                const int e  = kl & 1023;
                const int sl = (d == 0) ? s0 : ((d == 1) ? s1 : s2);
                const float v = __hip_atomic_load(
                    ring + (((size_t)sl * BB + g * BPG + b2) << 10) + e,
                    __ATOMIC_RELAXED, __HIP_MEMORY_SCOPE_AGENT);
                sa[kl * 4 + b2] = v;
            }
        }
        __syncthreads();

        // ---- WAIT: straggler spread hidden under stage-A
        if (tid == 0) {
            const int target = 32 * (t + 1);
            while (__hip_atomic_load(&cnt[g * 32], __ATOMIC_ACQUIRE,
                                     __HIP_MEMORY_SCOPE_AGENT) < target)
                __builtin_amdgcn_s_sleep(2);
        }
        __syncthreads();

        // ---- readout (tile-0 block of each group): integrate step t
        if (tile == 0 && st) {
            float h = 0.0f;
            #pragma unroll
            for (int k3 = 0; k3 < NT; ++k3)
                h += __hip_atomic_load(hpart + ((((size_t)(t & 1) * NT + k3) * BB)
                                                + g * BPG + sb) * NOUT + nl,
                                       __ATOMIC_RELAXED, __HIP_MEMORY_SCOPE_AGENT);
            r = ALPHA_MEM_OUT * r + h;
            out[((size_t)(g * BPG + sb) * TT + t) * NOUT + nl] = r;
        }

        if (use_csr) {
            // ---- sparse GEMM: thread (colg,sub) owns col, 1/8 of its nz.
            // Padded slots are {k=0, v=0} -> broadcast read + FMA by zero.
            float a0 = 0.0f, a1 = 0.0f, a2 = 0.0f, a3 = 0.0f;
            #pragma unroll 4
            for (int i = 0; i < CAP / 8; ++i) {
                const uint2 pv = Pk[i * 8 + sub];
                const float v  = __uint_as_float(pv.y);
                const float4 av = *(const float4*)&sa[pv.x << 2];
                a0 = fmaf(av.x, v, a0);
                a1 = fmaf(av.y, v, a1);
                a2 = fmaf(av.z, v, a2);
                a3 = fmaf(av.w, v, a3);
            }
            __syncthreads();             // sa reads done; alias as red

            float* red = sa;             // red[o][9], o = colg*4 + batch (o<128)
            red[(colg * 4 + 0) * 9 + sub] = a0;
            red[(colg * 4 + 1) * 9 + sub] = a1;
            red[(colg * 4 + 2) * 9 + sub] = a2;
            red[(colg * 4 + 3) * 9 + sub] = a3;
            __syncthreads();

            if (st) {
                float syn = 0.0f;
                #pragma unroll
                for (int k2 = 0; k2 < 8; ++k2)
                    syn += red[(nl * 4 + sb) * 9 + k2];
                mem = ALPHA_MEM * mem + ia + syn - (spk ? 1.0f : 0.0f);
            }
            __syncthreads();             // red reads done before next staging
        } else {
            // ---- dense GEMM fallback (R9 path)
            float4 acc0 = {0,0,0,0}, acc1 = {0,0,0,0}, acc2 = {0,0,0,0}, acc3 = {0,0,0,0};
            if (use_W) {
                #pragma unroll 8
                for (int i = 0; i < 96; ++i) {
                    const int kk = gks + (i << 5);
                    const float4 av = *(const float4*)&sa[kk << 2];
                    const float4 wv4 = *(const float4*)(Wt + ((size_t)kk << 10));
                    acc0.x = fmaf(av.x, wv4.x, acc0.x); acc0.y = fmaf(av.x, wv4.y, acc0.y);
                    acc0.z = fmaf(av.x, wv4.z, acc0.z); acc0.w = fmaf(av.x, wv4.w, acc0.w);
                    acc1.x = fmaf(av.y, wv4.x, acc1.x); acc1.y = fmaf(av.y, wv4.y, acc1.y);
                    acc1.z = fmaf(av.y, wv4.z, acc1.z); acc1.w = fmaf(av.y, wv4.w, acc1.w);
                    acc2.x = fmaf(av.z, wv4.x, acc2.x); acc2.y = fmaf(av.z, wv4.y, acc2.y);
                    acc2.z = fmaf(av.z, wv4.z, acc2.z); acc2.w = fmaf(av.z, wv4.w, acc2.w);
                    acc3.x = fmaf(av.w, wv4.x, acc3.x); acc3.y = fmaf(av.w, wv4.y, acc3.y);
                    acc3.z = fmaf(av.w, wv4.z, acc3.z); acc3.w = fmaf(av.w, wv4.w, acc3.w);
                }
            } else {
                #pragma unroll 2
                for (int i = 0; i < 96; ++i) {
                    const int kk = gks + (i << 5);
                    const int e  = kk & 1023;
                    const float sg = s_sign[e];
                    const float4 dm = *(const float4*)(Dt + ((size_t)kk << 10));
                    const float4 wr = *(const float4*)(Rt + ((size_t)e << 10));
                    float4 wv4;
                    wv4.x = dm.x * (sg * fabsf(wr.x));
                    wv4.y = dm.y * (sg * fabsf(wr.y));
                    wv4.z = dm.z * (sg * fabsf(wr.z));
                    wv4.w = dm.w * (sg * fabsf(wr.w));
                    const float4 av = *(const float4*)&sa[kk << 2];
                    acc0.x = fmaf(av.x, wv4.x, acc0.x); acc0.y = fmaf(av.x, wv4.y, acc0.y);
                    acc0.z = fmaf(av.x, wv4.z, acc0.z); acc0.w = fmaf(av.x, wv4.w, acc0.w);
                    acc1.x = fmaf(av.y, wv4.x, acc1.x); acc1.y = fmaf(av.y, wv4.y, acc1.y);
                    acc1.z = fmaf(av.y, wv4.z, acc1.z); acc1.w = fmaf(av.y, wv4.w, acc1.w);
                    acc2.x = fmaf(av.z, wv4.x, acc2.x); acc2.y = fmaf(av.z, wv4.y, acc2.y);
                    acc2.z = fmaf(av.z, wv4.z, acc2.z); acc2.w = fmaf(av.z, wv4.w, acc2.w);
                    acc3.x = fmaf(av.w, wv4.x, acc3.x); acc3.y = fmaf(av.w, wv4.y, acc3.y);
                    acc3.z = fmaf(av.w, wv4.z, acc3.z); acc3.w = fmaf(av.w, wv4.w, acc3.w);
                }
            }
            __syncthreads();             // sa reads done; alias as red

            float* red = sa;             // red[o][33], o = b2*32 + gcg*4 + j
            {
                const int o0 = gcg * 4;
                red[(0 * 32 + o0 + 0) * 33 + gks] = acc0.x;
                red[(0 * 32 + o0 + 1) * 33 + gks] = acc0.y;
                red[(0 * 32 + o0 + 2) * 33 + gks] = acc0.z;
                red[(0 * 32 + o0 + 3) * 33 + gks] = acc0.w;
                red[(1 * 32 + o0 + 0) * 33 + gks] = acc1.x;
                red[(1 * 32 + o0 + 1) * 33 + gks] = acc1.y;
                red[(1 * 32 + o0 + 2) * 33 + gks] = acc1.z;
                red[(1 * 32 + o0 + 3) * 33 + gks] = acc1.w;
                red[(2 * 32 + o0 + 0) * 33 + gks] = acc2.x;
                red[(2 * 32 + o0 + 1) * 33 + gks] = acc2.y;
                red[(2 * 32 + o0 + 2) * 33 + gks] = acc2.z;
                red[(2 * 32 + o0 + 3) * 33 + gks] = acc2.w;
                red[(3 * 32 + o0 + 0) * 33 + gks] = acc3.x;
                red[(3 * 32 + o0 + 1) * 33 + gks] = acc3.y;
                red[(3 * 32 + o0 + 2) * 33 + gks] = acc3.z;
                red[(3 * 32 + o0 + 3) * 33 + gks] = acc3.w;
            }
            __syncthreads();

            if (st) {
                float syn = 0.0f;
                #pragma unroll
                for (int k2 = 0; k2 < 32; ++k2)
                    syn += red[tid * 33 + k2];
                mem = ALPHA_MEM * mem + ia + syn - (spk ? 1.0f : 0.0f);
            }
            __syncthreads();             // red reads done before next staging
        }
    }
}

// ---------------------------------------------------------------------------
extern "C" void kernel_launch(void* const* d_in, const int* in_sizes, int n_in,
                              void* d_out, int out_size, void* d_ws, size_t ws_size,
                              hipStream_t stream) {
    const float* inputs  = (const float*)d_in[0];
    const float* w       = (const float*)d_in[1];
    const float* w_in    = (const float*)d_in[2];
    const float* w_out   = (const float*)d_in[3];
    const float* w_signs = (const float*)d_in[4];
    const float* dmap    = (const float*)d_in[5];
    const float* p       = (const float*)d_in[6];
    const int*   delays  = (const int*)d_in[7];
    float*       outp    = (float*)d_out;

    // ws layout (floats): ring | cnt(padded) | hpart | W | inp_pre | csr
    const size_t ring_f = (size_t)LL6 * BB * NN;          // 393216
    const size_t cnt_f  = GG * 32;                        // 512
    const size_t hp_f   = (size_t)2 * NT * BB * NOUT;     // 131072
    const size_t W_f    = (size_t)DD * NN * NN;           // 3145728
    const size_t pre_f  = (size_t)TT * BB * NN;           // 26214400
    const size_t csr_f  = (size_t)NN * CAP * 2;           // 1638400 (uint2 = 2 floats)

    float* ws = (float*)d_ws;
    float* ring  = ws;
    int*   cntp  = (int*)(ws + ring_f);
    float* hpart = ws + ring_f + cnt_f;
    size_t used  = ring_f + cnt_f + hp_f;

    int use_W = 0, use_pre = 0, use_csr = 0;
    float *W = nullptr, *inp_pre = nullptr;
    uint2 *pack = nullptr;
    if (ws_size >= (used + W_f) * 4)   { use_W = 1;   W = ws + used;       used += W_f; }
    if (ws_size >= (used + pre_f) * 4) { use_pre = 1; inp_pre = ws + used; used += pre_f; }
    if (use_W && ws_size >= (used + csr_f) * 4) {
        use_csr = 1; pack = (uint2*)(ws + used); used += csr_f;
    }

    if (use_W) {
        const int total = DD * NN * NN;
        build_W<<<(total + 255) / 256, 256, 0, stream>>>(w, w_signs, dmap, W);
    }
    if (use_csr)
        build_csr<<<NN, 256, 0, stream>>>(W, pack);
    if (use_pre) {
        const int total = TT * BB * NN;
        gemm_in<<<(total + 255) / 256, 256, 0, stream>>>(inputs, w_in, inp_pre);
    }
    {
        const int total = (int)(ring_f + cnt_f);   // ring + counters
        zero_sc1<<<(total + 255) / 256, 256, 0, stream>>>(ring, total);
    }

    void* args[] = {
        (void*)&inputs, (void*)&w_in, (void*)&w_out, (void*)&p, (void*)&delays,
        (void*)&W, (void*)&w, (void*)&w_signs, (void*)&dmap,
        (void*)&ring, (void*)&cntp, (void*)&hpart, (void*)&inp_pre, (void*)&pack,
        (void*)&outp, (void*)&use_pre, (void*)&use_W, (void*)&use_csr
    };
    hipError_t cerr = hipLaunchCooperativeKernel((const void*)snn_scan,
                               dim3(GG * NT), dim3(256), args, 0, stream);
    if (cerr != hipSuccess) {
        // Cooperative launch rejected: fall back to a plain launch. 512 blocks
        // at 2 blocks/CU (LDS-limited) on 256 CUs are co-resident physically,
        // so the agent-scope spin barrier still functions.
        hipLaunchKernelGGL(snn_scan, dim3(GG * NT), dim3(256), 0, stream,
                           inputs, w_in, w_out, p, delays, W, w, w_signs, dmap,
                           ring, cntp, hpart, inp_pre, pack, outp,
                           use_pre, use_W, use_csr);
    }
}

// Round 11
// 10505.544 us; speedup vs baseline: 1.4881x; 1.0419x over previous
//
#include <hip/hip_runtime.h>
#include <cstdint>
#include <cstddef>

// Problem constants
#define BB    64
#define TT    400
#define NN    1024
#define NIN   128
#define NOUT  32
#define DD    3
#define LL6   6        // ring length (delays 1,2,4)
#define GG    16       // batch groups
#define BPG   4        // batches per group
#define NT    32       // column tiles
#define KK    3072     // D*N
#define KP    (KK + 8) // padded plane stride (3080; mod 32 = 8 -> write 2-way)
#define CAP   800      // CSR capacity per column (mean 614, sd 22)

#define ALPHA_MEM     0.95f
#define ALPHA_MEM_OUT 0.95f
#define ALPHA_P       0.99f

// ---------------------------------------------------------------------------
__global__ void build_W(const float* __restrict__ w,
                        const float* __restrict__ w_signs,
                        const float* __restrict__ dmap,
                        float* __restrict__ W) {
    int idx = blockIdx.x * blockDim.x + threadIdx.x;
    if (idx >= DD * NN * NN) return;
    int en = idx % (NN * NN);
    int e  = en / NN;
    W[idx] = dmap[idx] * (w_signs[e] * fabsf(w[en]));
}

// Per-column CSR: pack[col][slot] = {u32 k, f32 val}, ascending k, zero-padded
// to CAP; ccnt[col] = nnz (clamped to CAP). Values bit-identical to dense W.
__global__ void build_csr(const float* __restrict__ W,
                          uint2* __restrict__ pack,
                          int*   __restrict__ ccnt) {
    const int col = blockIdx.x;           // 0..1023
    const int tid = threadIdx.x;          // 256 threads, 12 ks each
    __shared__ int pref[256];
    __shared__ int total_s;

    int cnt = 0;
    #pragma unroll
    for (int i = 0; i < 12; ++i) {
        const float v = W[(size_t)(tid * 12 + i) * NN + col];
        cnt += (v != 0.0f) ? 1 : 0;
    }
    pref[tid] = cnt;
    __syncthreads();
    if (tid == 0) {
        int run = 0;
        for (int j = 0; j < 256; ++j) { int c = pref[j]; pref[j] = run; run += c; }
        total_s = run;
        ccnt[col] = (run > CAP) ? CAP : run;
    }
    __syncthreads();

    int ofs = pref[tid];
    #pragma unroll
    for (int i = 0; i < 12; ++i) {
        const int k = tid * 12 + i;
        const float v = W[(size_t)k * NN + col];
        if (v != 0.0f && ofs < CAP) {
            pack[(size_t)col * CAP + ofs] = make_uint2((unsigned)k, __float_as_uint(v));
            ++ofs;
        }
    }
    for (int s = total_s + tid; s < CAP; s += 256)
        pack[(size_t)col * CAP + s] = make_uint2(0u, 0u);   // k=0, v=0.0f
}

// inp_pre laid out [t][b][n]
__global__ void gemm_in(const float* __restrict__ inputs,
                        const float* __restrict__ w_in,
                        float* __restrict__ inp) {
    int idx = blockIdx.x * blockDim.x + threadIdx.x;
    if (idx >= TT * BB * NN) return;
    int n  = idx & (NN - 1);
    int tb = idx >> 10;
    int b  = tb & 63;
    int t  = tb >> 6;
    const float* row = inputs + ((size_t)b * TT + t) * NIN;
    float acc = 0.0f;
    #pragma unroll 8
    for (int c = 0; c < NIN; ++c)
        acc = fmaf(row[c], w_in[c * NN + n], acc);
    inp[idx] = acc;
}

// zero through the coherent point so agent-scope readers see it
__global__ void zero_sc1(float* __restrict__ p, int n) {
    int i = blockIdx.x * blockDim.x + threadIdx.x;
    if (i < n)
        __hip_atomic_store(p + i, 0.0f, __ATOMIC_RELAXED, __HIP_MEMORY_SCOPE_AGENT);
}

// ---------------------------------------------------------------------------
// 512 blocks x 256 threads, 2 blocks/CU. Block (g=bid>>5, tile=bid&31) owns
// states (4 batches x 32 cols). Structure identical to R10 (verified PASS).
// R11 deltas: (1) sa stored as 4 batch-PLANES sap[b][k] (stride KP) so the
// sparse gather is 4x ds_read_b32 spread over 32 banks (~2-way) instead of
// ds_read_b128 confined to 8 bank-groups (~8-way conflict, 5.3e8 cycles);
// (2) per-column nnz counts trim the gather loop from CAP=800 to ~660.
// ---------------------------------------------------------------------------
__global__ __launch_bounds__(256, 2) void snn_scan(
    const float* __restrict__ inputs,
    const float* __restrict__ w_in,
    const float* __restrict__ w_out,
    const float* __restrict__ p,
    const int*   __restrict__ delays,
    const float* __restrict__ W,        // (KK,NN) materialized (use_W)
    const float* __restrict__ w_raw,
    const float* __restrict__ w_signs,
    const float* __restrict__ dmap,
    float*       __restrict__ ring,     // (LL6,BB,NN)
    int*         __restrict__ cnt,      // (GG*32) padded barrier counters
    float*       __restrict__ hpart,    // (2,NT,BB,NOUT)
    const float* __restrict__ inp_pre,  // (T,B,N) or null
    const uint2* __restrict__ pack,     // (NN,CAP) CSR or null
    const int*   __restrict__ ccnt,     // (NN) nnz per column or null
    float*       __restrict__ out,      // (B,T,NOUT)
    int use_pre, int use_W, int use_csr)
{
    __shared__ __align__(16) float sap[4 * KP];    // 48.1 KB planes; aliased as red[]
    __shared__ float w_out_s[32 * NOUT];           // 4 KB
    __shared__ float spk_s[BPG * 32];              // 512 B
    __shared__ float s_sign[NN];                   // 4 KB (fallback)
    __shared__ float s_in[BPG * NIN];              // 2 KB (fallback)

    const int bid  = blockIdx.x;
    const int g    = bid >> 5;          // 0..15
    const int tile = bid & 31;          // 0..31 (bid%8 = tile%8 -> XCD locality)
    const int tid  = threadIdx.x;
    const int lane = tid & 63;
    const int wv   = tid >> 6;

    const bool st = (tid < BPG * 32);   // 128 state threads
    const int  sb = tid >> 5;           // batch in group (state role)
    const int  nl = tid & 31;           // col in tile   (state role)

    const int gks = tid >> 3;           // k-split 0..31 (dense GEMM role)
    const int gcg = tid & 7;            // col group 0..7 (dense GEMM role)

    const int colg = tid >> 3;          // 0..31: column owned (sparse role)
    const int sub  = tid & 7;           // 0..7 : nz-split  (sparse role)

    float mem = 0.0f, wp = 0.0f, r = 0.0f;
    float pn = 0.0f, depr = 0.0f;
    if (st) { pn = p[tile * 32 + nl]; depr = (pn < 0.0f) ? 1.0f : 0.0f; }

    const int d0 = delays[0], d1 = delays[1], d2 = delays[2];

    for (int k = tid; k < 32 * NOUT; k += 256)
        w_out_s[k] = w_out[(tile * 32 + (k >> 5)) * NOUT + (k & 31)];
    if (!use_W)
        for (int k = tid; k < NN; k += 256) s_sign[k] = w_signs[k];
    __syncthreads();

    const float* Wt = W     + tile * 32 + gcg * 4;
    const float* Dt = dmap  + tile * 32 + gcg * 4;
    const float* Rt = w_raw + tile * 32 + gcg * 4;
    const uint2* Pk = pack  + (size_t)(tile * 32 + colg) * CAP;
    int niter = 0;
    if (use_csr) niter = (ccnt[tile * 32 + colg] + 7) >> 3;

    for (int t = 0; t < TT; ++t) {
        const int slot_w = t % LL6;
        const int s0 = (t - d0 + 2 * LL6) % LL6;
        const int s1 = (t - d1 + 2 * LL6) % LL6;
        const int s2 = (t - d2 + 2 * LL6) % LL6;

        // ---- phase 1: spike, publish ring (IF), wp update, ia prefetch
        bool  spk = false;
        float ia  = 0.0f;
        if (st) {
            spk = (mem - 1.0f) > 0.0f;
            const float a = spk ? (1.0f + wp) : 0.0f;
            __hip_atomic_store(ring + (((size_t)slot_w * BB + g * BPG + sb) << 10)
                                    + tile * 32 + nl,
                               a, __ATOMIC_RELAXED, __HIP_MEMORY_SCOPE_AGENT);
            wp = ALPHA_P * wp + (spk ? pn * (1.0f + depr * wp) : 0.0f);
            spk_s[tid] = spk ? 1.0f : 0.0f;
            if (use_pre)
                ia = inp_pre[((size_t)t * BB + g * BPG + sb) * NN + tile * 32 + nl];
        }
        if (!use_pre) {
            for (int k = tid; k < BPG * NIN; k += 256) {
                int b2 = k >> 7, c = k & 127;
                s_in[k] = inputs[((size_t)(g * BPG + b2) * TT + t) * NIN + c];
            }
        }
        __syncthreads();

        // ---- phase 2: readout partial for this tile
        if (st) {
            float h = 0.0f;
            #pragma unroll
            for (int n2 = 0; n2 < 32; ++n2)
                h = fmaf(spk_s[sb * 32 + n2], w_out_s[n2 * 32 + nl], h);
            __hip_atomic_store(hpart + ((((size_t)(t & 1) * NT + tile) * BB)
                                        + g * BPG + sb) * NOUT + nl,
                               h, __ATOMIC_RELAXED, __HIP_MEMORY_SCOPE_AGENT);
            if (!use_pre) {
                #pragma unroll 8
                for (int c = 0; c < NIN; ++c)
                    ia = fmaf(s_in[sb * NIN + c], w_in[c * NN + tile * 32 + nl], ia);
            }
        }
        __syncthreads();   // all waves' IF stores drained (vmcnt 0) before arrive

        // ---- ARRIVE (release); wait deferred past stage-A
        if (tid == 0)
            __hip_atomic_fetch_add(&cnt[g * 32], 1, __ATOMIC_RELEASE,
                                   __HIP_MEMORY_SCOPE_AGENT);

        // ---- stage A into planes: sap[b][k] (needs only barrier(t-1))
        {
            const int b2 = lane >> 4;       // batch 0..3
            const int eo = lane & 15;       // e offset within 16-chunk
            #pragma unroll 16
            for (int i = 0; i < 48; ++i) {
                const int c  = i * 4 + wv;          // 16-wide k-chunk 0..191
                const int kl = c * 16 + eo;         // k index 0..3071
                const int d  = kl >> 10;
                const int e  = kl & 1023;
                const int sl = (d == 0) ? s0 : ((d == 1) ? s1 : s2);
                const float v = __hip_atomic_load(
                    ring + (((size_t)sl * BB + g * BPG + b2) << 10) + e,
                    __ATOMIC_RELAXED, __HIP_MEMORY_SCOPE_AGENT);
                sap[b2 * KP + kl] = v;
            }
        }
        __syncthreads();

        // ---- WAIT: straggler spread hidden under stage-A
        if (tid == 0) {
            const int target = 32 * (t + 1);
            while (__hip_atomic_load(&cnt[g * 32], __ATOMIC_ACQUIRE,
                                     __HIP_MEMORY_SCOPE_AGENT) < target)
                __builtin_amdgcn_s_sleep(2);
        }
        __syncthreads();

        // ---- readout (tile-0 block of each group): integrate step t
        if (tile == 0 && st) {
            float h = 0.0f;
            #pragma unroll
            for (int k3 = 0; k3 < NT; ++k3)
                h += __hip_atomic_load(hpart + ((((size_t)(t & 1) * NT + k3) * BB)
                                                + g * BPG + sb) * NOUT + nl,
                                       __ATOMIC_RELAXED, __HIP_MEMORY_SCOPE_AGENT);
            r = ALPHA_MEM_OUT * r + h;
            out[((size_t)(g * BPG + sb) * TT + t) * NOUT + nl] = r;
        }

        if (use_csr) {
            // ---- sparse GEMM: thread (colg,sub) owns col, 1/8 of its nz.
            // Scalar plane reads: 64 random banks/instr (~2-way) vs b128 8-way.
            float a0 = 0.0f, a1 = 0.0f, a2 = 0.0f, a3 = 0.0f;
            #pragma unroll 4
            for (int i = 0; i < niter; ++i) {
                const uint2 pv = Pk[i * 8 + sub];
                const float v  = __uint_as_float(pv.y);
                const int   k  = (int)pv.x;
                a0 = fmaf(sap[0 * KP + k], v, a0);
                a1 = fmaf(sap[1 * KP + k], v, a1);
                a2 = fmaf(sap[2 * KP + k], v, a2);
                a3 = fmaf(sap[3 * KP + k], v, a3);
            }
            __syncthreads();             // sap reads done; alias as red

            float* red = sap;            // red[o][9], o = colg*4 + batch (o<128)
            red[(colg * 4 + 0) * 9 + sub] = a0;
            red[(colg * 4 + 1) * 9 + sub] = a1;
            red[(colg * 4 + 2) * 9 + sub] = a2;
            red[(colg * 4 + 3) * 9 + sub] = a3;
            __syncthreads();

            if (st) {
                float syn = 0.0f;
                #pragma unroll
                for (int k2 = 0; k2 < 8; ++k2)
                    syn += red[(nl * 4 + sb) * 9 + k2];
                mem = ALPHA_MEM * mem + ia + syn - (spk ? 1.0f : 0.0f);
            }
            __syncthreads();             // red reads done before next staging
        } else {
            // ---- dense GEMM fallback (plane reads: 8-lane broadcast, conflict-free)
            float4 acc0 = {0,0,0,0}, acc1 = {0,0,0,0}, acc2 = {0,0,0,0}, acc3 = {0,0,0,0};
            if (use_W) {
                #pragma unroll 8
                for (int i = 0; i < 96; ++i) {
                    const int kk = gks + (i << 5);
                    const float4 av = make_float4(sap[0 * KP + kk], sap[1 * KP + kk],
                                                  sap[2 * KP + kk], sap[3 * KP + kk]);
                    const float4 wv4 = *(const float4*)(Wt + ((size_t)kk << 10));
                    acc0.x = fmaf(av.x, wv4.x, acc0.x); acc0.y = fmaf(av.x, wv4.y, acc0.y);
                    acc0.z = fmaf(av.x, wv4.z, acc0.z); acc0.w = fmaf(av.x, wv4.w, acc0.w);
                    acc1.x = fmaf(av.y, wv4.x, acc1.x); acc1.y = fmaf(av.y, wv4.y, acc1.y);
                    acc1.z = fmaf(av.y, wv4.z, acc1.z); acc1.w = fmaf(av.y, wv4.w, acc1.w);
                    acc2.x = fmaf(av.z, wv4.x, acc2.x); acc2.y = fmaf(av.z, wv4.y, acc2.y);
                    acc2.z = fmaf(av.z, wv4.z, acc2.z); acc2.w = fmaf(av.z, wv4.w, acc2.w);
                    acc3.x = fmaf(av.w, wv4.x, acc3.x); acc3.y = fmaf(av.w, wv4.y, acc3.y);
                    acc3.z = fmaf(av.w, wv4.z, acc3.z); acc3.w = fmaf(av.w, wv4.w, acc3.w);
                }
            } else {
                #pragma unroll 2
                for (int i = 0; i < 96; ++i) {
                    const int kk = gks + (i << 5);
                    const int e  = kk & 1023;
                    const float sg = s_sign[e];
                    const float4 dm = *(const float4*)(Dt + ((size_t)kk << 10));
                    const float4 wr = *(const float4*)(Rt + ((size_t)e << 10));
                    float4 wv4;
                    wv4.x = dm.x * (sg * fabsf(wr.x));
                    wv4.y = dm.y * (sg * fabsf(wr.y));
                    wv4.z = dm.z * (sg * fabsf(wr.z));
                    wv4.w = dm.w * (sg * fabsf(wr.w));
                    const float4 av = make_float4(sap[0 * KP + kk], sap[1 * KP + kk],
                                                  sap[2 * KP + kk], sap[3 * KP + kk]);
                    acc0.x = fmaf(av.x, wv4.x, acc0.x); acc0.y = fmaf(av.x, wv4.y, acc0.y);
                    acc0.z = fmaf(av.x, wv4.z, acc0.z); acc0.w = fmaf(av.x, wv4.w, acc0.w);
                    acc1.x = fmaf(av.y, wv4.x, acc1.x); acc1.y = fmaf(av.y, wv4.y, acc1.y);
                    acc1.z = fmaf(av.y, wv4.z, acc1.z); acc1.w = fmaf(av.y, wv4.w, acc1.w);
                    acc2.x = fmaf(av.z, wv4.x, acc2.x); acc2.y = fmaf(av.z, wv4.y, acc2.y);
                    acc2.z = fmaf(av.z, wv4.z, acc2.z); acc2.w = fmaf(av.z, wv4.w, acc2.w);
                    acc3.x = fmaf(av.w, wv4.x, acc3.x); acc3.y = fmaf(av.w, wv4.y, acc3.y);
                    acc3.z = fmaf(av.w, wv4.z, acc3.z); acc3.w = fmaf(av.w, wv4.w, acc3.w);
                }
            }
            __syncthreads();             // sap reads done; alias as red

            float* red = sap;            // red[o][33], o = b2*32 + gcg*4 + j
            {
                const int o0 = gcg * 4;
                red[(0 * 32 + o0 + 0) * 33 + gks] = acc0.x;
                red[(0 * 32 + o0 + 1) * 33 + gks] = acc0.y;
                red[(0 * 32 + o0 + 2) * 33 + gks] = acc0.z;
                red[(0 * 32 + o0 + 3) * 33 + gks] = acc0.w;
                red[(1 * 32 + o0 + 0) * 33 + gks] = acc1.x;
                red[(1 * 32 + o0 + 1) * 33 + gks] = acc1.y;
                red[(1 * 32 + o0 + 2) * 33 + gks] = acc1.z;
                red[(1 * 32 + o0 + 3) * 33 + gks] = acc1.w;
                red[(2 * 32 + o0 + 0) * 33 + gks] = acc2.x;
                red[(2 * 32 + o0 + 1) * 33 + gks] = acc2.y;
                red[(2 * 32 + o0 + 2) * 33 + gks] = acc2.z;
                red[(2 * 32 + o0 + 3) * 33 + gks] = acc2.w;
                red[(3 * 32 + o0 + 0) * 33 + gks] = acc3.x;
                red[(3 * 32 + o0 + 1) * 33 + gks] = acc3.y;
                red[(3 * 32 + o0 + 2) * 33 + gks] = acc3.z;
                red[(3 * 32 + o0 + 3) * 33 + gks] = acc3.w;
            }
            __syncthreads();

            if (st) {
                float syn = 0.0f;
                #pragma unroll
                for (int k2 = 0; k2 < 32; ++k2)
                    syn += red[tid * 33 + k2];
                mem = ALPHA_MEM * mem + ia + syn - (spk ? 1.0f : 0.0f);
            }
            __syncthreads();             // red reads done before next staging
        }
    }
}

// ---------------------------------------------------------------------------
extern "C" void kernel_launch(void* const* d_in, const int* in_sizes, int n_in,
                              void* d_out, int out_size, void* d_ws, size_t ws_size,
                              hipStream_t stream) {
    const float* inputs  = (const float*)d_in[0];
    const float* w       = (const float*)d_in[1];
    const float* w_in    = (const float*)d_in[2];
    const float* w_out   = (const float*)d_in[3];
    const float* w_signs = (const float*)d_in[4];
    const float* dmap    = (const float*)d_in[5];
    const float* p       = (const float*)d_in[6];
    const int*   delays  = (const int*)d_in[7];
    float*       outp    = (float*)d_out;

    // ws layout (floats): ring | cnt(padded) | hpart | W | inp_pre | pack | ccnt
    const size_t ring_f = (size_t)LL6 * BB * NN;          // 393216
    const size_t cnt_f  = GG * 32;                        // 512
    const size_t hp_f   = (size_t)2 * NT * BB * NOUT;     // 131072
    const size_t W_f    = (size_t)DD * NN * NN;           // 3145728
    const size_t pre_f  = (size_t)TT * BB * NN;           // 26214400
    const size_t csr_f  = (size_t)NN * CAP * 2;           // 1638400 (uint2 = 2 floats)
    const size_t cc_f   = NN;                             // 1024

    float* ws = (float*)d_ws;
    float* ring  = ws;
    int*   cntp  = (int*)(ws + ring_f);
    float* hpart = ws + ring_f + cnt_f;
    size_t used  = ring_f + cnt_f + hp_f;

    int use_W = 0, use_pre = 0, use_csr = 0;
    float *W = nullptr, *inp_pre = nullptr;
    uint2 *pack = nullptr;
    int   *ccnt = nullptr;
    if (ws_size >= (used + W_f) * 4)   { use_W = 1;   W = ws + used;       used += W_f; }
    if (ws_size >= (used + pre_f) * 4) { use_pre = 1; inp_pre = ws + used; used += pre_f; }
    if (use_W && ws_size >= (used + csr_f + cc_f) * 4) {
        use_csr = 1;
        pack = (uint2*)(ws + used); used += csr_f;
        ccnt = (int*)(ws + used);   used += cc_f;
    }

    if (use_W) {
        const int total = DD * NN * NN;
        build_W<<<(total + 255) / 256, 256, 0, stream>>>(w, w_signs, dmap, W);
    }
    if (use_csr)
        build_csr<<<NN, 256, 0, stream>>>(W, pack, ccnt);
    if (use_pre) {
        const int total = TT * BB * NN;
        gemm_in<<<(total + 255) / 256, 256, 0, stream>>>(inputs, w_in, inp_pre);
    }
    {
        const int total = (int)(ring_f + cnt_f);   // ring + counters
        zero_sc1<<<(total + 255) / 256, 256, 0, stream>>>(ring, total);
    }

    void* args[] = {
        (void*)&inputs, (void*)&w_in, (void*)&w_out, (void*)&p, (void*)&delays,
        (void*)&W, (void*)&w, (void*)&w_signs, (void*)&dmap,
        (void*)&ring, (void*)&cntp, (void*)&hpart, (void*)&inp_pre, (void*)&pack,
        (void*)&ccnt, (void*)&outp, (void*)&use_pre, (void*)&use_W, (void*)&use_csr
    };
    hipError_t cerr = hipLaunchCooperativeKernel((const void*)snn_scan,
                               dim3(GG * NT), dim3(256), args, 0, stream);
    if (cerr != hipSuccess) {
        // Cooperative launch rejected: fall back to a plain launch. 512 blocks
        // at 2 blocks/CU (LDS-limited) on 256 CUs are co-resident physically,
        // so the agent-scope spin barrier still functions.
        hipLaunchKernelGGL(snn_scan, dim3(GG * NT), dim3(256), 0, stream,
                           inputs, w_in, w_out, p, delays, W, w, w_signs, dmap,
                           ring, cntp, hpart, inp_pre, pack, ccnt, outp,
                           use_pre, use_W, use_csr);
    }
}

// Round 12
// 10176.299 us; speedup vs baseline: 1.5363x; 1.0324x over previous
//
#include <hip/hip_runtime.h>
#include <cstdint>
#include <cstddef>

// Problem constants
#define BB    64
#define TT    400
#define NN    1024
#define NIN   128
#define NOUT  32
#define DD    3
#define LL6   6        // ring length (delays 1,2,4)
#define GG    16       // batch groups
#define BPG   4        // batches per group
#define NT    32       // column tiles
#define KK    3072     // D*N
#define CAP   800      // CSR capacity per column (mean 614, sd 22)

#define ALPHA_MEM     0.95f
#define ALPHA_MEM_OUT 0.95f
#define ALPHA_P       0.99f

// ---------------------------------------------------------------------------
__global__ void build_W(const float* __restrict__ w,
                        const float* __restrict__ w_signs,
                        const float* __restrict__ dmap,
                        float* __restrict__ W) {
    int idx = blockIdx.x * blockDim.x + threadIdx.x;
    if (idx >= DD * NN * NN) return;
    int en = idx % (NN * NN);
    int e  = en / NN;
    W[idx] = dmap[idx] * (w_signs[e] * fabsf(w[en]));
}

// Per-column CSR: pack[col][slot] = {u32 k, f32 val}, ascending k, zero-padded
// to CAP; ccnt[col] = nnz (clamped to CAP). Values bit-identical to dense W.
__global__ void build_csr(const float* __restrict__ W,
                          uint2* __restrict__ pack,
                          int*   __restrict__ ccnt) {
    const int col = blockIdx.x;           // 0..1023
    const int tid = threadIdx.x;          // 256 threads, 12 ks each
    __shared__ int pref[256];
    __shared__ int total_s;

    int cnt = 0;
    #pragma unroll
    for (int i = 0; i < 12; ++i) {
        const float v = W[(size_t)(tid * 12 + i) * NN + col];
        cnt += (v != 0.0f) ? 1 : 0;
    }
    pref[tid] = cnt;
    __syncthreads();
    if (tid == 0) {
        int run = 0;
        for (int j = 0; j < 256; ++j) { int c = pref[j]; pref[j] = run; run += c; }
        total_s = run;
        ccnt[col] = (run > CAP) ? CAP : run;
    }
    __syncthreads();

    int ofs = pref[tid];
    #pragma unroll
    for (int i = 0; i < 12; ++i) {
        const int k = tid * 12 + i;
        const float v = W[(size_t)k * NN + col];
        if (v != 0.0f && ofs < CAP) {
            pack[(size_t)col * CAP + ofs] = make_uint2((unsigned)k, __float_as_uint(v));
            ++ofs;
        }
    }
    for (int s = total_s + tid; s < CAP; s += 256)
        pack[(size_t)col * CAP + s] = make_uint2(0u, 0u);   // k=0, v=0.0f
}

// inp_pre laid out [t][b][n]
__global__ void gemm_in(const float* __restrict__ inputs,
                        const float* __restrict__ w_in,
                        float* __restrict__ inp) {
    int idx = blockIdx.x * blockDim.x + threadIdx.x;
    if (idx >= TT * BB * NN) return;
    int n  = idx & (NN - 1);
    int tb = idx >> 10;
    int b  = tb & 63;
    int t  = tb >> 6;
    const float* row = inputs + ((size_t)b * TT + t) * NIN;
    float acc = 0.0f;
    #pragma unroll 8
    for (int c = 0; c < NIN; ++c)
        acc = fmaf(row[c], w_in[c * NN + n], acc);
    inp[idx] = acc;
}

// zero through the coherent point so agent-scope readers see it
__global__ void zero_sc1(float* __restrict__ p, int n) {
    int i = blockIdx.x * blockDim.x + threadIdx.x;
    if (i < n)
        __hip_atomic_store(p + i, 0.0f, __ATOMIC_RELAXED, __HIP_MEMORY_SCOPE_AGENT);
}

// ---------------------------------------------------------------------------
// 512 blocks x 256 threads, 2 blocks/CU. Block (g=bid>>5, tile=bid&31) owns
// states (4 batches x 32 cols). Structure identical to R11 (verified PASS).
// R12 delta: gather back to float4 sa[k*4+b] via ds_read_b128 (measured 26
// conflict-cy/iter vs scalar-plane 62), keeping R11's per-column nnz trim.
// ---------------------------------------------------------------------------
__global__ __launch_bounds__(256, 2) void snn_scan(
    const float* __restrict__ inputs,
    const float* __restrict__ w_in,
    const float* __restrict__ w_out,
    const float* __restrict__ p,
    const int*   __restrict__ delays,
    const float* __restrict__ W,        // (KK,NN) materialized (use_W)
    const float* __restrict__ w_raw,
    const float* __restrict__ w_signs,
    const float* __restrict__ dmap,
    float*       __restrict__ ring,     // (LL6,BB,NN)
    int*         __restrict__ cnt,      // (GG*32) padded barrier counters
    float*       __restrict__ hpart,    // (2,NT,BB,NOUT)
    const float* __restrict__ inp_pre,  // (T,B,N) or null
    const uint2* __restrict__ pack,     // (NN,CAP) CSR or null
    const int*   __restrict__ ccnt,     // (NN) nnz per column or null
    float*       __restrict__ out,      // (B,T,NOUT)
    int use_pre, int use_W, int use_csr)
{
    __shared__ __align__(16) float sa[KK * BPG];   // 48 KB; aliased as red[] post-GEMM
    __shared__ float w_out_s[32 * NOUT];           // 4 KB
    __shared__ float spk_s[BPG * 32];              // 512 B
    __shared__ float s_sign[NN];                   // 4 KB (fallback)
    __shared__ float s_in[BPG * NIN];              // 2 KB (fallback)

    const int bid  = blockIdx.x;
    const int g    = bid >> 5;          // 0..15
    const int tile = bid & 31;          // 0..31 (bid%8 = tile%8 -> XCD locality)
    const int tid  = threadIdx.x;
    const int lane = tid & 63;
    const int wv   = tid >> 6;

    const bool st = (tid < BPG * 32);   // 128 state threads
    const int  sb = tid >> 5;           // batch in group (state role)
    const int  nl = tid & 31;           // col in tile   (state role)

    const int gks = tid >> 3;           // k-split 0..31 (dense GEMM role)
    const int gcg = tid & 7;            // col group 0..7 (dense GEMM role)

    const int colg = tid >> 3;          // 0..31: column owned (sparse role)
    const int sub  = tid & 7;           // 0..7 : nz-split  (sparse role)

    float mem = 0.0f, wp = 0.0f, r = 0.0f;
    float pn = 0.0f, depr = 0.0f;
    if (st) { pn = p[tile * 32 + nl]; depr = (pn < 0.0f) ? 1.0f : 0.0f; }

    const int d0 = delays[0], d1 = delays[1], d2 = delays[2];

    for (int k = tid; k < 32 * NOUT; k += 256)
        w_out_s[k] = w_out[(tile * 32 + (k >> 5)) * NOUT + (k & 31)];
    if (!use_W)
        for (int k = tid; k < NN; k += 256) s_sign[k] = w_signs[k];
    __syncthreads();

    const float* Wt = W     + tile * 32 + gcg * 4;
    const float* Dt = dmap  + tile * 32 + gcg * 4;
    const float* Rt = w_raw + tile * 32 + gcg * 4;
    const uint2* Pk = pack  + (size_t)(tile * 32 + colg) * CAP;
    int niter = 0;
    if (use_csr) niter = (ccnt[tile * 32 + colg] + 7) >> 3;

    for (int t = 0; t < TT; ++t) {
        const int slot_w = t % LL6;
        const int s0 = (t - d0 + 2 * LL6) % LL6;
        const int s1 = (t - d1 + 2 * LL6) % LL6;
        const int s2 = (t - d2 + 2 * LL6) % LL6;

        // ---- phase 1: spike, publish ring (IF), wp update, ia prefetch
        bool  spk = false;
        float ia  = 0.0f;
        if (st) {
            spk = (mem - 1.0f) > 0.0f;
            const float a = spk ? (1.0f + wp) : 0.0f;
            __hip_atomic_store(ring + (((size_t)slot_w * BB + g * BPG + sb) << 10)
                                    + tile * 32 + nl,
                               a, __ATOMIC_RELAXED, __HIP_MEMORY_SCOPE_AGENT);
            wp = ALPHA_P * wp + (spk ? pn * (1.0f + depr * wp) : 0.0f);
            spk_s[tid] = spk ? 1.0f : 0.0f;
            if (use_pre)
                ia = inp_pre[((size_t)t * BB + g * BPG + sb) * NN + tile * 32 + nl];
        }
        if (!use_pre) {
            for (int k = tid; k < BPG * NIN; k += 256) {
                int b2 = k >> 7, c = k & 127;
                s_in[k] = inputs[((size_t)(g * BPG + b2) * TT + t) * NIN + c];
            }
        }
        __syncthreads();

        // ---- phase 2: readout partial for this tile
        if (st) {
            float h = 0.0f;
            #pragma unroll
            for (int n2 = 0; n2 < 32; ++n2)
                h = fmaf(spk_s[sb * 32 + n2], w_out_s[n2 * 32 + nl], h);
            __hip_atomic_store(hpart + ((((size_t)(t & 1) * NT + tile) * BB)
                                        + g * BPG + sb) * NOUT + nl,
                               h, __ATOMIC_RELAXED, __HIP_MEMORY_SCOPE_AGENT);
            if (!use_pre) {
                #pragma unroll 8
                for (int c = 0; c < NIN; ++c)
                    ia = fmaf(s_in[sb * NIN + c], w_in[c * NN + tile * 32 + nl], ia);
            }
        }
        __syncthreads();   // all waves' IF stores drained (vmcnt 0) before arrive

        // ---- ARRIVE (release); wait deferred past stage-A
        if (tid == 0)
            __hip_atomic_fetch_add(&cnt[g * 32], 1, __ATOMIC_RELEASE,
                                   __HIP_MEMORY_SCOPE_AGENT);

        // ---- stage A transposed: sa[k*4 + b] (needs only barrier(t-1))
        {
            const int b2 = lane >> 4;       // batch 0..3
            const int eo = lane & 15;       // e offset within 16-chunk
            #pragma unroll 16
            for (int i = 0; i < 48; ++i) {
                const int c  = i * 4 + wv;          // 16-wide k-chunk 0..191
                const int kl = c * 16 + eo;         // k index 0..3071
                const int d  = kl >> 10;
                const int e  = kl & 1023;
                const int sl = (d == 0) ? s0 : ((d == 1) ? s1 : s2);
                const float v = __hip_atomic_load(
                    ring + (((size_t)sl * BB + g * BPG + b2) << 10) + e,
                    __ATOMIC_RELAXED, __HIP_MEMORY_SCOPE_AGENT);
                sa[kl * 4 + b2] = v;
            }
        }
        __syncthreads();

        // ---- WAIT: straggler spread hidden under stage-A
        if (tid == 0) {
            const int target = 32 * (t + 1);
            while (__hip_atomic_load(&cnt[g * 32], __ATOMIC_ACQUIRE,
                                     __HIP_MEMORY_SCOPE_AGENT) < target)
                __builtin_amdgcn_s_sleep(2);
        }
        __syncthreads();

        // ---- readout (tile-0 block of each group): integrate step t
        if (tile == 0 && st) {
            float h = 0.0f;
            #pragma unroll
            for (int k3 = 0; k3 < NT; ++k3)
                h += __hip_atomic_load(hpart + ((((size_t)(t & 1) * NT + k3) * BB)
                                                + g * BPG + sb) * NOUT + nl,
                                       __ATOMIC_RELAXED, __HIP_MEMORY_SCOPE_AGENT);
            r = ALPHA_MEM_OUT * r + h;
            out[((size_t)(g * BPG + sb) * TT + t) * NOUT + nl] = r;
        }

        if (use_csr) {
            // ---- sparse GEMM: thread (colg,sub) owns col, 1/8 of its nz.
            // b128 gather: 4 sub-phases x 16 lanes x 4-bank spans (~26 cy/iter).
            float a0 = 0.0f, a1 = 0.0f, a2 = 0.0f, a3 = 0.0f;
            #pragma unroll 4
            for (int i = 0; i < niter; ++i) {
                const uint2 pv = Pk[i * 8 + sub];
                const float v  = __uint_as_float(pv.y);
                const float4 av = *(const float4*)&sa[pv.x << 2];
                a0 = fmaf(av.x, v, a0);
                a1 = fmaf(av.y, v, a1);
                a2 = fmaf(av.z, v, a2);
                a3 = fmaf(av.w, v, a3);
            }
            __syncthreads();             // sa reads done; alias as red

            float* red = sa;             // red[o][9], o = colg*4 + batch (o<128)
            red[(colg * 4 + 0) * 9 + sub] = a0;
            red[(colg * 4 + 1) * 9 + sub] = a1;
            red[(colg * 4 + 2) * 9 + sub] = a2;
            red[(colg * 4 + 3) * 9 + sub] = a3;
            __syncthreads();

            if (st) {
                float syn = 0.0f;
                #pragma unroll
                for (int k2 = 0; k2 < 8; ++k2)
                    syn += red[(nl * 4 + sb) * 9 + k2];
                mem = ALPHA_MEM * mem + ia + syn - (spk ? 1.0f : 0.0f);
            }
            __syncthreads();             // red reads done before next staging
        } else {
            // ---- dense GEMM fallback (R10 path)
            float4 acc0 = {0,0,0,0}, acc1 = {0,0,0,0}, acc2 = {0,0,0,0}, acc3 = {0,0,0,0};
            if (use_W) {
                #pragma unroll 8
                for (int i = 0; i < 96; ++i) {
                    const int kk = gks + (i << 5);
                    const float4 av = *(const float4*)&sa[kk << 2];
                    const float4 wv4 = *(const float4*)(Wt + ((size_t)kk << 10));
                    acc0.x = fmaf(av.x, wv4.x, acc0.x); acc0.y = fmaf(av.x, wv4.y, acc0.y);
                    acc0.z = fmaf(av.x, wv4.z, acc0.z); acc0.w = fmaf(av.x, wv4.w, acc0.w);
                    acc1.x = fmaf(av.y, wv4.x, acc1.x); acc1.y = fmaf(av.y, wv4.y, acc1.y);
                    acc1.z = fmaf(av.y, wv4.z, acc1.z); acc1.w = fmaf(av.y, wv4.w, acc1.w);
                    acc2.x = fmaf(av.z, wv4.x, acc2.x); acc2.y = fmaf(av.z, wv4.y, acc2.y);
                    acc2.z = fmaf(av.z, wv4.z, acc2.z); acc2.w = fmaf(av.z, wv4.w, acc2.w);
                    acc3.x = fmaf(av.w, wv4.x, acc3.x); acc3.y = fmaf(av.w, wv4.y, acc3.y);
                    acc3.z = fmaf(av.w, wv4.z, acc3.z); acc3.w = fmaf(av.w, wv4.w, acc3.w);
                }
            } else {
                #pragma unroll 2
                for (int i = 0; i < 96; ++i) {
                    const int kk = gks + (i << 5);
                    const int e  = kk & 1023;
                    const float sg = s_sign[e];
                    const float4 dm = *(const float4*)(Dt + ((size_t)kk << 10));
                    const float4 wr = *(const float4*)(Rt + ((size_t)e << 10));
                    float4 wv4;
                    wv4.x = dm.x * (sg * fabsf(wr.x));
                    wv4.y = dm.y * (sg * fabsf(wr.y));
                    wv4.z = dm.z * (sg * fabsf(wr.z));
                    wv4.w = dm.w * (sg * fabsf(wr.w));
                    const float4 av = *(const float4*)&sa[kk << 2];
                    acc0.x = fmaf(av.x, wv4.x, acc0.x); acc0.y = fmaf(av.x, wv4.y, acc0.y);
                    acc0.z = fmaf(av.x, wv4.z, acc0.z); acc0.w = fmaf(av.x, wv4.w, acc0.w);
                    acc1.x = fmaf(av.y, wv4.x, acc1.x); acc1.y = fmaf(av.y, wv4.y, acc1.y);
                    acc1.z = fmaf(av.y, wv4.z, acc1.z); acc1.w = fmaf(av.y, wv4.w, acc1.w);
                    acc2.x = fmaf(av.z, wv4.x, acc2.x); acc2.y = fmaf(av.z, wv4.y, acc2.y);
                    acc2.z = fmaf(av.z, wv4.z, acc2.z); acc2.w = fmaf(av.z, wv4.w, acc2.w);
                    acc3.x = fmaf(av.w, wv4.x, acc3.x); acc3.y = fmaf(av.w, wv4.y, acc3.y);
                    acc3.z = fmaf(av.w, wv4.z, acc3.z); acc3.w = fmaf(av.w, wv4.w, acc3.w);
                }
            }
            __syncthreads();             // sa reads done; alias as red

            float* red = sa;             // red[o][33], o = b2*32 + gcg*4 + j
            {
                const int o0 = gcg * 4;
                red[(0 * 32 + o0 + 0) * 33 + gks] = acc0.x;
                red[(0 * 32 + o0 + 1) * 33 + gks] = acc0.y;
                red[(0 * 32 + o0 + 2) * 33 + gks] = acc0.z;
                red[(0 * 32 + o0 + 3) * 33 + gks] = acc0.w;
                red[(1 * 32 + o0 + 0) * 33 + gks] = acc1.x;
                red[(1 * 32 + o0 + 1) * 33 + gks] = acc1.y;
                red[(1 * 32 + o0 + 2) * 33 + gks] = acc1.z;
                red[(1 * 32 + o0 + 3) * 33 + gks] = acc1.w;
                red[(2 * 32 + o0 + 0) * 33 + gks] = acc2.x;
                red[(2 * 32 + o0 + 1) * 33 + gks] = acc2.y;
                red[(2 * 32 + o0 + 2) * 33 + gks] = acc2.z;
                red[(2 * 32 + o0 + 3) * 33 + gks] = acc2.w;
                red[(3 * 32 + o0 + 0) * 33 + gks] = acc3.x;
                red[(3 * 32 + o0 + 1) * 33 + gks] = acc3.y;
                red[(3 * 32 + o0 + 2) * 33 + gks] = acc3.z;
                red[(3 * 32 + o0 + 3) * 33 + gks] = acc3.w;
            }
            __syncthreads();

            if (st) {
                float syn = 0.0f;
                #pragma unroll
                for (int k2 = 0; k2 < 32; ++k2)
                    syn += red[tid * 33 + k2];
                mem = ALPHA_MEM * mem + ia + syn - (spk ? 1.0f : 0.0f);
            }
            __syncthreads();             // red reads done before next staging
        }
    }
}

// ---------------------------------------------------------------------------
extern "C" void kernel_launch(void* const* d_in, const int* in_sizes, int n_in,
                              void* d_out, int out_size, void* d_ws, size_t ws_size,
                              hipStream_t stream) {
    const float* inputs  = (const float*)d_in[0];
    const float* w       = (const float*)d_in[1];
    const float* w_in    = (const float*)d_in[2];
    const float* w_out   = (const float*)d_in[3];
    const float* w_signs = (const float*)d_in[4];
    const float* dmap    = (const float*)d_in[5];
    const float* p       = (const float*)d_in[6];
    const int*   delays  = (const int*)d_in[7];
    float*       outp    = (float*)d_out;

    // ws layout (floats): ring | cnt(padded) | hpart | W | inp_pre | pack | ccnt
    const size_t ring_f = (size_t)LL6 * BB * NN;          // 393216
    const size_t cnt_f  = GG * 32;                        // 512
    const size_t hp_f   = (size_t)2 * NT * BB * NOUT;     // 131072
    const size_t W_f    = (size_t)DD * NN * NN;           // 3145728
    const size_t pre_f  = (size_t)TT * BB * NN;           // 26214400
    const size_t csr_f  = (size_t)NN * CAP * 2;           // 1638400 (uint2 = 2 floats)
    const size_t cc_f   = NN;                             // 1024

    float* ws = (float*)d_ws;
    float* ring  = ws;
    int*   cntp  = (int*)(ws + ring_f);
    float* hpart = ws + ring_f + cnt_f;
    size_t used  = ring_f + cnt_f + hp_f;

    int use_W = 0, use_pre = 0, use_csr = 0;
    float *W = nullptr, *inp_pre = nullptr;
    uint2 *pack = nullptr;
    int   *ccnt = nullptr;
    if (ws_size >= (used + W_f) * 4)   { use_W = 1;   W = ws + used;       used += W_f; }
    if (ws_size >= (used + pre_f) * 4) { use_pre = 1; inp_pre = ws + used; used += pre_f; }
    if (use_W && ws_size >= (used + csr_f + cc_f) * 4) {
        use_csr = 1;
        pack = (uint2*)(ws + used); used += csr_f;
        ccnt = (int*)(ws + used);   used += cc_f;
    }

    if (use_W) {
        const int total = DD * NN * NN;
        build_W<<<(total + 255) / 256, 256, 0, stream>>>(w, w_signs, dmap, W);
    }
    if (use_csr)
        build_csr<<<NN, 256, 0, stream>>>(W, pack, ccnt);
    if (use_pre) {
        const int total = TT * BB * NN;
        gemm_in<<<(total + 255) / 256, 256, 0, stream>>>(inputs, w_in, inp_pre);
    }
    {
        const int total = (int)(ring_f + cnt_f);   // ring + counters
        zero_sc1<<<(total + 255) / 256, 256, 0, stream>>>(ring, total);
    }

    void* args[] = {
        (void*)&inputs, (void*)&w_in, (void*)&w_out, (void*)&p, (void*)&delays,
        (void*)&W, (void*)&w, (void*)&w_signs, (void*)&dmap,
        (void*)&ring, (void*)&cntp, (void*)&hpart, (void*)&inp_pre, (void*)&pack,
        (void*)&ccnt, (void*)&outp, (void*)&use_pre, (void*)&use_W, (void*)&use_csr
    };
    hipError_t cerr = hipLaunchCooperativeKernel((const void*)snn_scan,
                               dim3(GG * NT), dim3(256), args, 0, stream);
    if (cerr != hipSuccess) {
        // Cooperative launch rejected: fall back to a plain launch. 512 blocks
        // at 2 blocks/CU (LDS-limited) on 256 CUs are co-resident physically,
        // so the agent-scope spin barrier still functions.
        hipLaunchKernelGGL(snn_scan, dim3(GG * NT), dim3(256), 0, stream,
                           inputs, w_in, w_out, p, delays, W, w, w_signs, dmap,
                           ring, cntp, hpart, inp_pre, pack, ccnt, outp,
                           use_pre, use_W, use_csr);
    }
}